// Round 1
// baseline (606.388 us; speedup 1.0000x reference)
//
#include <hip/hip_runtime.h>

#define N_NODES 30000
#define N_EDGES 480000
#define D 128
#define H 3
#define BN_EPS 1e-5f

// ---------------- GEMM: out = epilogue(X @ W + bias) ----------------
// BM=64 rows, BN=128 cols (=D), K=128 (=D). 256 threads; per-thread 4 rows x 8 cols.
// X tile staged in LDS (pad to 132 words: column reads land on 2 banks -> free
// 2-way). W streamed from global (L1/L2-resident, broadcast across row-groups).
#define BM 64
#define LDX 132

template <int MODE>  // 0 = BN+ReLU write, 1 = bias write, 2 = bias accumulate
__global__ __launch_bounds__(256) void gemm_k(
    const float* __restrict__ X, const float* __restrict__ W,
    const float* __restrict__ bias,
    const float* __restrict__ gam, const float* __restrict__ bet,
    const float* __restrict__ mu, const float* __restrict__ var,
    float* __restrict__ out, int nrows)
{
    __shared__ float Xs[BM * LDX];
    const int tid = threadIdx.x;
    const int row0 = blockIdx.x * BM;

    // stage 64x128 floats = 2048 float4 (byte offset r*528 + 16*c4 is 16B-aligned)
    for (int f = tid; f < BM * 32; f += 256) {
        const int r = f >> 5;
        const int c4 = (f & 31) << 2;
        float4 val = make_float4(0.f, 0.f, 0.f, 0.f);
        const int gr = row0 + r;
        if (gr < nrows) val = *(const float4*)(X + (size_t)gr * D + c4);
        *(float4*)(&Xs[r * LDX + c4]) = val;
    }
    __syncthreads();

    const int cg = tid & 15;   // col group: cols cg*8 .. cg*8+7
    const int rg = tid >> 4;   // row group: rows rg*4 .. rg*4+3
    const int colbase = cg * 8;

    float acc[4][8];
#pragma unroll
    for (int i = 0; i < 4; ++i)
#pragma unroll
        for (int j = 0; j < 8; ++j) acc[i][j] = 0.f;

    const float* Wp = W + colbase;
#pragma unroll 4
    for (int k = 0; k < D; ++k) {
        const float4 w0 = *(const float4*)(Wp + (size_t)k * D);
        const float4 w1 = *(const float4*)(Wp + (size_t)k * D + 4);
        const float wv[8] = {w0.x, w0.y, w0.z, w0.w, w1.x, w1.y, w1.z, w1.w};
#pragma unroll
        for (int i = 0; i < 4; ++i) {
            const float xv = Xs[(rg * 4 + i) * LDX + k];
#pragma unroll
            for (int j = 0; j < 8; ++j) acc[i][j] = fmaf(xv, wv[j], acc[i][j]);
        }
    }

    // epilogue coefficients per column
    float sc[8], of[8];
#pragma unroll
    for (int j = 0; j < 8; ++j) {
        const int c = colbase + j;
        if constexpr (MODE == 0) {
            const float s = gam[c] * rsqrtf(var[c] + BN_EPS);
            sc[j] = s;
            of[j] = (bias[c] - mu[c]) * s + bet[c];
        } else {
            sc[j] = 1.f;
            of[j] = bias[c];
        }
    }

#pragma unroll
    for (int i = 0; i < 4; ++i) {
        const int gr = row0 + rg * 4 + i;
        if (gr >= nrows) continue;
        float* op = out + (size_t)gr * D + colbase;
        float v[8];
#pragma unroll
        for (int j = 0; j < 8; ++j) {
            float t = acc[i][j] * sc[j] + of[j];
            if constexpr (MODE == 0) t = fmaxf(t, 0.f);
            v[j] = t;
        }
        if constexpr (MODE == 2) {
            const float4 p0 = *(const float4*)(op);
            const float4 p1 = *(const float4*)(op + 4);
            v[0] += p0.x; v[1] += p0.y; v[2] += p0.z; v[3] += p0.w;
            v[4] += p1.x; v[5] += p1.y; v[6] += p1.z; v[7] += p1.w;
        }
        *(float4*)(op)     = make_float4(v[0], v[1], v[2], v[3]);
        *(float4*)(op + 4) = make_float4(v[4], v[5], v[6], v[7]);
    }
}

// ---------------- CSR build ----------------
__global__ void count_k(const int* __restrict__ dst, int* __restrict__ counts) {
    const int e = blockIdx.x * 256 + threadIdx.x;
    if (e < N_EDGES) atomicAdd(&counts[dst[e]], 1);
}

__global__ __launch_bounds__(1024) void scan_k(const int* __restrict__ counts,
                                               int* __restrict__ offs,
                                               int* __restrict__ pos, int n) {
    __shared__ int sh[1024];
    const int tid = threadIdx.x;
    int carry = 0;
    for (int base = 0; base < n; base += 1024) {
        const int i = base + tid;
        const int v = (i < n) ? counts[i] : 0;
        sh[tid] = v;
        __syncthreads();
        int val = v;
        for (int off = 1; off < 1024; off <<= 1) {
            const int t = (tid >= off) ? sh[tid - off] : 0;
            __syncthreads();
            val += t;
            sh[tid] = val;
            __syncthreads();
        }
        if (i < n) {
            const int ex = carry + val - v;
            offs[i] = ex;
            pos[i] = ex;
        }
        const int tot = sh[1023];
        __syncthreads();
        carry += tot;
    }
    if (tid == 0) offs[n] = carry;
}

__global__ void fill_k(const int* __restrict__ src, const int* __restrict__ dst,
                       int* __restrict__ pos, int* __restrict__ srcs) {
    const int e = blockIdx.x * 256 + threadIdx.x;
    if (e < N_EDGES) {
        const int d = dst[e];
        const int p = atomicAdd(&pos[d], 1);
        srcs[p] = src[e];
    }
}

// ---------------- GIN aggregation: z = (1+eps)*x + sum_{j->i} x_j ----------------
// one wave per node; lane l covers cols 2l, 2l+1 (float2 -> 512B coalesced rows)
__global__ __launch_bounds__(256) void agg_k(const float* __restrict__ x,
                                             const int* __restrict__ offs,
                                             const int* __restrict__ srcs,
                                             const float* __restrict__ epsk,
                                             float* __restrict__ z) {
    const int node = blockIdx.x * 4 + (threadIdx.x >> 6);
    if (node >= N_NODES) return;
    const int lane = threadIdx.x & 63;
    const float a = 1.0f + epsk[0];
    const float2* x2 = (const float2*)x;

    const float2 xv = x2[(size_t)node * 64 + lane];
    float ax = a * xv.x, ay = a * xv.y;
    float bx = 0.f, by = 0.f;

    const int beg = offs[node], end = offs[node + 1];
    int i = beg;
    for (; i + 1 < end; i += 2) {
        const int s0 = srcs[i];
        const int s1 = srcs[i + 1];
        const float2 v0 = x2[(size_t)s0 * 64 + lane];
        const float2 v1 = x2[(size_t)s1 * 64 + lane];
        ax += v0.x; ay += v0.y;
        bx += v1.x; by += v1.y;
    }
    if (i < end) {
        const int s = srcs[i];
        const float2 v = x2[(size_t)s * 64 + lane];
        ax += v.x; ay += v.y;
    }
    float2 o; o.x = ax + bx; o.y = ay + by;
    ((float2*)z)[(size_t)node * 64 + lane] = o;
}

// ---------------- driver ----------------
extern "C" void kernel_launch(void* const* d_in, const int* in_sizes, int n_in,
                              void* d_out, int out_size, void* d_ws, size_t ws_size,
                              hipStream_t stream)
{
    const float* xs  = (const float*)d_in[0];
    const int*   ei  = (const int*)d_in[1];
    const float* lW1 = (const float*)d_in[2];
    const float* lb1 = (const float*)d_in[3];
    const float* lg  = (const float*)d_in[4];
    const float* lbt = (const float*)d_in[5];
    const float* lm  = (const float*)d_in[6];
    const float* lv  = (const float*)d_in[7];
    const float* lW2 = (const float*)d_in[8];
    const float* lb2 = (const float*)d_in[9];
    const float* eps = (const float*)d_in[10];
    const float* cW1 = (const float*)d_in[11];
    const float* cb1 = (const float*)d_in[12];
    const float* cg  = (const float*)d_in[13];
    const float* cbt = (const float*)d_in[14];
    const float* cm  = (const float*)d_in[15];
    const float* cv  = (const float*)d_in[16];
    const float* cW2 = (const float*)d_in[17];
    const float* cb2 = (const float*)d_in[18];
    float* out = (float*)d_out;

    char* ws = (char*)d_ws;
    float* tmpA = (float*)ws;            ws += (size_t)N_NODES * D * sizeof(float);
    int* counts = (int*)ws;              ws += (size_t)(N_NODES + 64) * sizeof(int);
    int* offs   = (int*)ws;              ws += (size_t)(N_NODES + 64) * sizeof(int);
    int* pos    = (int*)ws;              ws += (size_t)(N_NODES + 64) * sizeof(int);
    int* srcs   = (int*)ws;

    const int gemmGrid = (N_NODES + BM - 1) / BM;
    const int edgeGrid = (N_EDGES + 255) / 256;

    // lin: tmpA = relu(bn(xs0 @ lW1 + lb1)); out = tmpA @ lW2 + lb2
    gemm_k<0><<<gemmGrid, 256, 0, stream>>>(xs, lW1, lb1, lg, lbt, lm, lv, tmpA, N_NODES);
    gemm_k<1><<<gemmGrid, 256, 0, stream>>>(tmpA, lW2, lb2, nullptr, nullptr, nullptr, nullptr, out, N_NODES);

    for (int k = 0; k < H; ++k) {
        const int* src = ei + ((size_t)k * 2 + 0) * N_EDGES;
        const int* dst = ei + ((size_t)k * 2 + 1) * N_EDGES;
        const float* x = xs + (size_t)(k + 1) * N_NODES * D;

        hipMemsetAsync(counts, 0, N_NODES * sizeof(int), stream);
        count_k<<<edgeGrid, 256, 0, stream>>>(dst, counts);
        scan_k<<<1, 1024, 0, stream>>>(counts, offs, pos, N_NODES);
        fill_k<<<edgeGrid, 256, 0, stream>>>(src, dst, pos, srcs);
        agg_k<<<(N_NODES + 3) / 4, 256, 0, stream>>>(x, offs, srcs, eps + k, tmpA);

        // in-place: tmpA = relu(bn(tmpA @ cW1 + cb1)); out += tmpA @ cW2 + cb2
        gemm_k<0><<<gemmGrid, 256, 0, stream>>>(tmpA, cW1 + (size_t)k * D * D, cb1 + (size_t)k * D,
                                                cg + (size_t)k * D, cbt + (size_t)k * D,
                                                cm + (size_t)k * D, cv + (size_t)k * D, tmpA, N_NODES);
        gemm_k<2><<<gemmGrid, 256, 0, stream>>>(tmpA, cW2 + (size_t)k * D * D, cb2 + (size_t)k * D,
                                                nullptr, nullptr, nullptr, nullptr, out, N_NODES);
    }
}

// Round 2
// 512.337 us; speedup vs baseline: 1.1836x; 1.1836x over previous
//
#include <hip/hip_runtime.h>

#define N_NODES 30000
#define N_EDGES 480000
#define D 128
#define H 3
#define BN_EPS 1e-5f
#define M_TOT (H * N_NODES)          // 90000 concatenated counters
#define E_TOT (H * N_EDGES)          // 1440000 edges
#define SCAN_NBLK ((M_TOT + 1023) / 1024)   // 88

// ---------------- Fused layer: out (=|+=) relu(bn(X@W1+b1)) @ W2 + b2 -------
// BM=64 rows/block, 256 threads, per-thread 4 rows x 8 cols. K=D=128 is fully
// in-block, so the second GEMM runs on the h-tile staged back into the same
// LDS buffer. Removes the 15 MB intermediate HBM round-trip per layer.
#define BM 64
#define LDX 132   // +4 pad: row-group stride 528 words -> 2-way bank alias (free)

template <int ACC>   // 0 = write out, 1 = accumulate into out
__global__ __launch_bounds__(256) void layer_k(
    const float* __restrict__ X,
    const float* __restrict__ W1, const float* __restrict__ b1,
    const float* __restrict__ gam, const float* __restrict__ bet,
    const float* __restrict__ mu, const float* __restrict__ var,
    const float* __restrict__ W2, const float* __restrict__ b2,
    float* __restrict__ out, int nrows)
{
    __shared__ float Xs[BM * LDX];
    const int tid = threadIdx.x;
    const int row0 = blockIdx.x * BM;

    // stage X tile (64x128) as float4
    for (int f = tid; f < BM * 32; f += 256) {
        const int r = f >> 5;
        const int c4 = (f & 31) << 2;
        float4 val = make_float4(0.f, 0.f, 0.f, 0.f);
        const int gr = row0 + r;
        if (gr < nrows) val = *(const float4*)(X + (size_t)gr * D + c4);
        *(float4*)(&Xs[r * LDX + c4]) = val;
    }

    const int cg = tid & 15;          // col group: cols cg*8..cg*8+7
    const int rg = tid >> 4;          // row group: rows rg*4..rg*4+3
    const int colbase = cg * 8;

    // BN coefficients for this thread's 8 columns
    float sc1[8], of1[8];
#pragma unroll
    for (int j = 0; j < 8; ++j) {
        const int c = colbase + j;
        const float s = gam[c] * rsqrtf(var[c] + BN_EPS);
        sc1[j] = s;
        of1[j] = (b1[c] - mu[c]) * s + bet[c];
    }

    __syncthreads();

    float acc[4][8];
#pragma unroll
    for (int i = 0; i < 4; ++i)
#pragma unroll
        for (int j = 0; j < 8; ++j) acc[i][j] = 0.f;

    // ---- GEMM 1: h = relu(bn(X @ W1 + b1)) ----
    const float* Wp = W1 + colbase;
#pragma unroll 4
    for (int k = 0; k < D; ++k) {
        const float4 w0 = *(const float4*)(Wp + (size_t)k * D);
        const float4 w1 = *(const float4*)(Wp + (size_t)k * D + 4);
        const float wv[8] = {w0.x, w0.y, w0.z, w0.w, w1.x, w1.y, w1.z, w1.w};
#pragma unroll
        for (int i = 0; i < 4; ++i) {
            const float xv = Xs[(rg * 4 + i) * LDX + k];
#pragma unroll
            for (int j = 0; j < 8; ++j) acc[i][j] = fmaf(xv, wv[j], acc[i][j]);
        }
    }

    __syncthreads();   // everyone done reading Xs before overwrite

    // epilogue 1 + stage h into the same LDS buffer
#pragma unroll
    for (int i = 0; i < 4; ++i) {
        float* hp = &Xs[(rg * 4 + i) * LDX + colbase];
        float v[8];
#pragma unroll
        for (int j = 0; j < 8; ++j)
            v[j] = fmaxf(acc[i][j] * sc1[j] + of1[j], 0.f);
        *(float4*)(hp)     = make_float4(v[0], v[1], v[2], v[3]);
        *(float4*)(hp + 4) = make_float4(v[4], v[5], v[6], v[7]);
    }

    __syncthreads();

    // ---- GEMM 2: out (=|+=) h @ W2 + b2 ----
    float acc2[4][8];
#pragma unroll
    for (int i = 0; i < 4; ++i)
#pragma unroll
        for (int j = 0; j < 8; ++j) acc2[i][j] = 0.f;

    const float* Wp2 = W2 + colbase;
#pragma unroll 4
    for (int k = 0; k < D; ++k) {
        const float4 w0 = *(const float4*)(Wp2 + (size_t)k * D);
        const float4 w1 = *(const float4*)(Wp2 + (size_t)k * D + 4);
        const float wv[8] = {w0.x, w0.y, w0.z, w0.w, w1.x, w1.y, w1.z, w1.w};
#pragma unroll
        for (int i = 0; i < 4; ++i) {
            const float xv = Xs[(rg * 4 + i) * LDX + k];
#pragma unroll
            for (int j = 0; j < 8; ++j) acc2[i][j] = fmaf(xv, wv[j], acc2[i][j]);
        }
    }

#pragma unroll
    for (int i = 0; i < 4; ++i) {
        const int gr = row0 + rg * 4 + i;
        if (gr >= nrows) continue;
        float* op = out + (size_t)gr * D + colbase;
        float v[8];
#pragma unroll
        for (int j = 0; j < 8; ++j) v[j] = acc2[i][j] + b2[colbase + j];
        if constexpr (ACC == 1) {
            const float4 p0 = *(const float4*)(op);
            const float4 p1 = *(const float4*)(op + 4);
            v[0] += p0.x; v[1] += p0.y; v[2] += p0.z; v[3] += p0.w;
            v[4] += p1.x; v[5] += p1.y; v[6] += p1.z; v[7] += p1.w;
        }
        *(float4*)(op)     = make_float4(v[0], v[1], v[2], v[3]);
        *(float4*)(op + 4) = make_float4(v[4], v[5], v[6], v[7]);
    }
}

// ---------------- CSR build (all 3 hops batched) ----------------
// counts/offs/pos are concatenated [H][N]; since each hop totals exactly E,
// a global exclusive scan gives hop-k offsets into the global srcs[3E] array.
__global__ void count_all_k(const int* __restrict__ ei, int* __restrict__ counts) {
    const int e = blockIdx.x * 256 + threadIdx.x;
    if (e < E_TOT) {
        const int hop = e / N_EDGES;
        const int idx = e - hop * N_EDGES;
        const int d = ei[(size_t)hop * 2 * N_EDGES + N_EDGES + idx];
        atomicAdd(&counts[hop * N_NODES + d], 1);
    }
}

// phase A: per-block (1024 elems) exclusive scan + block sums
__global__ __launch_bounds__(1024) void scanA_k(const int* __restrict__ counts,
                                                int* __restrict__ local,
                                                int* __restrict__ bsums) {
    __shared__ int sh[1024];
    const int tid = threadIdx.x;
    const int i = blockIdx.x * 1024 + tid;
    const int v = (i < M_TOT) ? counts[i] : 0;
    sh[tid] = v;
    __syncthreads();
    int val = v;
    for (int off = 1; off < 1024; off <<= 1) {
        const int t = (tid >= off) ? sh[tid - off] : 0;
        __syncthreads();
        val += t;
        sh[tid] = val;
        __syncthreads();
    }
    if (i < M_TOT) local[i] = val - v;           // exclusive
    if (tid == 1023) bsums[blockIdx.x] = val;    // block total
}

// phase B: single block scans the 88 block sums (exclusive, in place)
__global__ __launch_bounds__(128) void scanB_k(int* __restrict__ bsums, int nb) {
    __shared__ int sh[128];
    const int tid = threadIdx.x;
    const int v = (tid < nb) ? bsums[tid] : 0;
    sh[tid] = v;
    __syncthreads();
    int val = v;
    for (int off = 1; off < 128; off <<= 1) {
        const int t = (tid >= off) ? sh[tid - off] : 0;
        __syncthreads();
        val += t;
        sh[tid] = val;
        __syncthreads();
    }
    if (tid < nb) bsums[tid] = val - v;
}

// phase C: add block offsets; duplicate into pos; write sentinel
__global__ __launch_bounds__(1024) void scanC_k(int* __restrict__ offs,
                                                const int* __restrict__ bsums,
                                                int* __restrict__ pos) {
    const int i = blockIdx.x * 1024 + threadIdx.x;
    if (i < M_TOT) {
        const int val = offs[i] + bsums[blockIdx.x];
        offs[i] = val;
        pos[i] = val;
    }
    if (i == 0) offs[M_TOT] = E_TOT;
}

__global__ void fill_all_k(const int* __restrict__ ei, int* __restrict__ pos,
                           int* __restrict__ srcs) {
    const int e = blockIdx.x * 256 + threadIdx.x;
    if (e < E_TOT) {
        const int hop = e / N_EDGES;
        const int idx = e - hop * N_EDGES;
        const int s = ei[(size_t)hop * 2 * N_EDGES + idx];
        const int d = ei[(size_t)hop * 2 * N_EDGES + N_EDGES + idx];
        const int p = atomicAdd(&pos[hop * N_NODES + d], 1);
        srcs[p] = s;
    }
}

// ---------------- GIN aggregation: z = (1+eps)*x + sum_{j->i} x_j ----------
// one wave per node; lane l covers cols 2l,2l+1; 4-way unrolled gather for ILP
__global__ __launch_bounds__(256) void agg_k(const float* __restrict__ x,
                                             const int* __restrict__ offs,
                                             const int* __restrict__ srcs,
                                             const float* __restrict__ epsk,
                                             float* __restrict__ z) {
    const int node = blockIdx.x * 4 + (threadIdx.x >> 6);
    if (node >= N_NODES) return;
    const int lane = threadIdx.x & 63;
    const float a = 1.0f + epsk[0];
    const float2* x2 = (const float2*)x;

    const float2 xv = x2[(size_t)node * 64 + lane];
    float ax = a * xv.x, ay = a * xv.y;
    float bx = 0.f, by = 0.f, cx = 0.f, cy = 0.f, dx = 0.f, dy = 0.f;

    const int beg = offs[node], end = offs[node + 1];
    int i = beg;
    for (; i + 3 < end; i += 4) {
        const int s0 = srcs[i], s1 = srcs[i + 1], s2 = srcs[i + 2], s3 = srcs[i + 3];
        const float2 v0 = x2[(size_t)s0 * 64 + lane];
        const float2 v1 = x2[(size_t)s1 * 64 + lane];
        const float2 v2 = x2[(size_t)s2 * 64 + lane];
        const float2 v3 = x2[(size_t)s3 * 64 + lane];
        ax += v0.x; ay += v0.y;
        bx += v1.x; by += v1.y;
        cx += v2.x; cy += v2.y;
        dx += v3.x; dy += v3.y;
    }
    for (; i < end; ++i) {
        const int s = srcs[i];
        const float2 v = x2[(size_t)s * 64 + lane];
        ax += v.x; ay += v.y;
    }
    float2 o;
    o.x = (ax + bx) + (cx + dx);
    o.y = (ay + by) + (cy + dy);
    ((float2*)z)[(size_t)node * 64 + lane] = o;
}

// ---------------- driver ----------------
extern "C" void kernel_launch(void* const* d_in, const int* in_sizes, int n_in,
                              void* d_out, int out_size, void* d_ws, size_t ws_size,
                              hipStream_t stream)
{
    const float* xs  = (const float*)d_in[0];
    const int*   ei  = (const int*)d_in[1];
    const float* lW1 = (const float*)d_in[2];
    const float* lb1 = (const float*)d_in[3];
    const float* lg  = (const float*)d_in[4];
    const float* lbt = (const float*)d_in[5];
    const float* lm  = (const float*)d_in[6];
    const float* lv  = (const float*)d_in[7];
    const float* lW2 = (const float*)d_in[8];
    const float* lb2 = (const float*)d_in[9];
    const float* eps = (const float*)d_in[10];
    const float* cW1 = (const float*)d_in[11];
    const float* cb1 = (const float*)d_in[12];
    const float* cg  = (const float*)d_in[13];
    const float* cbt = (const float*)d_in[14];
    const float* cm  = (const float*)d_in[15];
    const float* cv  = (const float*)d_in[16];
    const float* cW2 = (const float*)d_in[17];
    const float* cb2 = (const float*)d_in[18];
    float* out = (float*)d_out;

    char* ws = (char*)d_ws;
    float* tmpA = (float*)ws;  ws += (size_t)N_NODES * D * sizeof(float);
    int* counts = (int*)ws;    ws += (size_t)(M_TOT + 64) * sizeof(int);
    int* offs   = (int*)ws;    ws += (size_t)(M_TOT + 64) * sizeof(int);
    int* pos    = (int*)ws;    ws += (size_t)(M_TOT + 64) * sizeof(int);
    int* bsums  = (int*)ws;    ws += 128 * sizeof(int);
    int* srcs   = (int*)ws;

    const int gemmGrid = (N_NODES + BM - 1) / BM;
    const int edgeGrid = (E_TOT + 255) / 256;

    // CSR for all 3 hops, batched
    hipMemsetAsync(counts, 0, M_TOT * sizeof(int), stream);
    count_all_k<<<edgeGrid, 256, 0, stream>>>(ei, counts);
    scanA_k<<<SCAN_NBLK, 1024, 0, stream>>>(counts, offs, bsums);
    scanB_k<<<1, 128, 0, stream>>>(bsums, SCAN_NBLK);
    scanC_k<<<SCAN_NBLK, 1024, 0, stream>>>(offs, bsums, pos);
    fill_all_k<<<edgeGrid, 256, 0, stream>>>(ei, pos, srcs);

    // lin layer: out = relu(bn(xs0@lW1+lb1)) @ lW2 + lb2
    layer_k<0><<<gemmGrid, 256, 0, stream>>>(xs, lW1, lb1, lg, lbt, lm, lv,
                                             lW2, lb2, out, N_NODES);

    for (int k = 0; k < H; ++k) {
        const float* x = xs + (size_t)(k + 1) * N_NODES * D;
        agg_k<<<(N_NODES + 3) / 4, 256, 0, stream>>>(x, offs + (size_t)k * N_NODES,
                                                     srcs, eps + k, tmpA);
        layer_k<1><<<gemmGrid, 256, 0, stream>>>(tmpA,
                                                 cW1 + (size_t)k * D * D, cb1 + (size_t)k * D,
                                                 cg + (size_t)k * D, cbt + (size_t)k * D,
                                                 cm + (size_t)k * D, cv + (size_t)k * D,
                                                 cW2 + (size_t)k * D * D, cb2 + (size_t)k * D,
                                                 out, N_NODES);
    }
}

// Round 3
// 332.997 us; speedup vs baseline: 1.8210x; 1.5386x over previous
//
#include <hip/hip_runtime.h>

#define N_NODES 30000
#define N_EDGES 480000
#define D 128
#define H 3
#define BN_EPS 1e-5f
#define M_TOT (H * N_NODES)
#define E_TOT (H * N_EDGES)
#define SCAN_NBLK ((M_TOT + 1023) / 1024)   // 88

typedef __attribute__((ext_vector_type(8))) short short8v;   // 8 x bf16 (4 VGPRs)
typedef __attribute__((ext_vector_type(4))) float f32x4;     // MFMA accumulator

__device__ __forceinline__ ushort f2bf(float f) {            // RNE f32 -> bf16
    uint u = __float_as_uint(f);
    u += 0x7fffu + ((u >> 16) & 1u);
    return (ushort)(u >> 16);
}
__device__ __forceinline__ float bf2f(ushort b) {
    return __uint_as_float(((uint)b) << 16);
}

// ---------------- prep: f32 slice -> bf16 ----------------
__global__ __launch_bounds__(256) void conv_k(const float* __restrict__ src,
                                              ushort* __restrict__ dst, int n4) {
    const int i = blockIdx.x * 256 + threadIdx.x;
    if (i < n4) {
        const float4 v = ((const float4*)src)[i];
        ushort4 o;
        o.x = f2bf(v.x); o.y = f2bf(v.y); o.z = f2bf(v.z); o.w = f2bf(v.w);
        ((ushort4*)dst)[i] = o;
    }
}

// ---------------- prep: transpose+convert the 8 weight matrices -------------
// Wt[mat][n][k] = W[k][n] as bf16 (B-operand wants contiguous k per n)
__global__ __launch_bounds__(256) void prep_w_k(
    const float* __restrict__ lW1, const float* __restrict__ lW2,
    const float* __restrict__ cW1, const float* __restrict__ cW2,
    ushort* __restrict__ Wt)
{
    const int mat = blockIdx.x;
    const float* src;
    if (mat == 0) src = lW1;
    else if (mat == 1) src = lW2;
    else {
        const int k = (mat - 2) >> 1;
        src = ((mat & 1) == 0 ? cW1 : cW2) + (size_t)k * D * D;
    }
    ushort* dst = Wt + (size_t)mat * D * D;
    for (int idx = threadIdx.x; idx < D * D; idx += 256) {
        const int n = idx >> 7, k = idx & 127;
        dst[idx] = f2bf(src[k * D + n]);   // write coalesced, read via L1/L2
    }
}

// ---------------- prep: fold BN into scale/offset per layer ----------------
// scof[L][0][c] = gam*rsqrt(var+eps); scof[L][1][c] = (b1-mu)*s + bet
__global__ __launch_bounds__(512) void scof_k(
    const float* __restrict__ lb1, const float* __restrict__ lg,
    const float* __restrict__ lbt, const float* __restrict__ lm,
    const float* __restrict__ lv,
    const float* __restrict__ cb1, const float* __restrict__ cg,
    const float* __restrict__ cbt, const float* __restrict__ cm,
    const float* __restrict__ cv, float* __restrict__ scof)
{
    const int tid = threadIdx.x;
    const int L = tid >> 7, c = tid & 127;
    float g, v, b, m, bt;
    if (L == 0) { g = lg[c]; v = lv[c]; b = lb1[c]; m = lm[c]; bt = lbt[c]; }
    else {
        const int k = L - 1;
        g = cg[k * D + c]; v = cv[k * D + c]; b = cb1[k * D + c];
        m = cm[k * D + c]; bt = cbt[k * D + c];
    }
    const float s = g * rsqrtf(v + BN_EPS);
    scof[L * 256 + c] = s;
    scof[L * 256 + 128 + c] = (b - m) * s + bt;
}

// ---------------- Fused MFMA layer: out (=|+=) relu(bn(X@W1+b1)) @ W2 + b2 --
// 256 threads = 4 waves; 64 rows x 128 cols per block; K = D = 128.
// A frag: m = lane&15, k = (lane>>4)*8+j  |  B frag from Wt[n][k]: n = lane&15
// D frag: row = (lane>>4)*4+reg, col = lane&15   [verified m89 mapping]
#define LW 136   // LDS row stride (ushorts): 272B -> 16B-aligned frags, ~2-way banks

template <int ACC>
__global__ __launch_bounds__(256) void layer_k(
    const ushort* __restrict__ X, const ushort* __restrict__ W1t,
    const ushort* __restrict__ W2t, const float* __restrict__ scof,
    const float* __restrict__ b2, float* __restrict__ out, int nrows)
{
    __shared__ ushort Xs[64 * LW];    // A tile, reused for h tile
    __shared__ ushort Ws[128 * LW];   // B tile [n][k], W1 then W2
    const int tid = threadIdx.x;
    const int wave = tid >> 6, lane = tid & 63;
    const int m16 = lane & 15, kq = lane >> 4;
    const int row0 = blockIdx.x * 64;

    for (int f = tid; f < 2048; f += 256) {
        const int r = f >> 5, c8 = f & 31;
        ushort4 v = make_ushort4(0, 0, 0, 0);
        const int gr = row0 + r;
        if (gr < nrows) v = *(const ushort4*)(X + (size_t)gr * D + c8 * 4);
        *(ushort4*)(&Xs[r * LW + c8 * 4]) = v;
    }
    for (int f = tid; f < 4096; f += 256) {
        const int n = f >> 5, c8 = f & 31;
        *(ushort4*)(&Ws[n * LW + c8 * 4]) = *(const ushort4*)(W1t + n * D + c8 * 4);
    }
    __syncthreads();

    const int arow = wave * 16 + m16;
    f32x4 acc[8];
#pragma unroll
    for (int t = 0; t < 8; ++t) acc[t] = (f32x4){0.f, 0.f, 0.f, 0.f};

#pragma unroll
    for (int kk = 0; kk < 4; ++kk) {
        const short8v a = *(const short8v*)(&Xs[arow * LW + kk * 32 + kq * 8]);
#pragma unroll
        for (int t = 0; t < 8; ++t) {
            const short8v b = *(const short8v*)(&Ws[(t * 16 + m16) * LW + kk * 32 + kq * 8]);
            acc[t] = __builtin_amdgcn_mfma_f32_16x16x32_bf16(a, b, acc[t], 0, 0, 0);
        }
    }
    __syncthreads();   // all waves done reading Xs/Ws

    // epilogue 1: h = relu(bn(.)) -> bf16 back into Xs
#pragma unroll
    for (int t = 0; t < 8; ++t) {
        const int n = t * 16 + m16;
        const float sc = scof[n], of = scof[128 + n];
#pragma unroll
        for (int r = 0; r < 4; ++r) {
            const int m = wave * 16 + kq * 4 + r;
            Xs[m * LW + n] = f2bf(fmaxf(acc[t][r] * sc + of, 0.f));
        }
    }
    for (int f = tid; f < 4096; f += 256) {   // restage Ws with W2
        const int n = f >> 5, c8 = f & 31;
        *(ushort4*)(&Ws[n * LW + c8 * 4]) = *(const ushort4*)(W2t + n * D + c8 * 4);
    }
    __syncthreads();

    f32x4 acc2[8];
#pragma unroll
    for (int t = 0; t < 8; ++t) acc2[t] = (f32x4){0.f, 0.f, 0.f, 0.f};

#pragma unroll
    for (int kk = 0; kk < 4; ++kk) {
        const short8v a = *(const short8v*)(&Xs[arow * LW + kk * 32 + kq * 8]);
#pragma unroll
        for (int t = 0; t < 8; ++t) {
            const short8v b = *(const short8v*)(&Ws[(t * 16 + m16) * LW + kk * 32 + kq * 8]);
            acc2[t] = __builtin_amdgcn_mfma_f32_16x16x32_bf16(a, b, acc2[t], 0, 0, 0);
        }
    }

#pragma unroll
    for (int t = 0; t < 8; ++t) {
        const int n = t * 16 + m16;
        const float bb = b2[n];
#pragma unroll
        for (int r = 0; r < 4; ++r) {
            const int gr = row0 + wave * 16 + kq * 4 + r;
            if (gr < nrows) {
                float* p = out + (size_t)gr * D + n;
                float v = acc2[t][r] + bb;
                if (ACC) v += *p;
                *p = v;
            }
        }
    }
}

// ---------------- CSR build (all 3 hops batched) ----------------
__global__ void count_all_k(const int* __restrict__ ei, int* __restrict__ counts) {
    const int e = blockIdx.x * 256 + threadIdx.x;
    if (e < E_TOT) {
        const int hop = e / N_EDGES;
        const int idx = e - hop * N_EDGES;
        const int d = ei[(size_t)hop * 2 * N_EDGES + N_EDGES + idx];
        atomicAdd(&counts[hop * N_NODES + d], 1);
    }
}

__global__ __launch_bounds__(1024) void scanA_k(const int* __restrict__ counts,
                                                int* __restrict__ local,
                                                int* __restrict__ bsums) {
    __shared__ int sh[1024];
    const int tid = threadIdx.x;
    const int i = blockIdx.x * 1024 + tid;
    const int v = (i < M_TOT) ? counts[i] : 0;
    sh[tid] = v;
    __syncthreads();
    int val = v;
    for (int off = 1; off < 1024; off <<= 1) {
        const int t = (tid >= off) ? sh[tid - off] : 0;
        __syncthreads();
        val += t;
        sh[tid] = val;
        __syncthreads();
    }
    if (i < M_TOT) local[i] = val - v;
    if (tid == 1023) bsums[blockIdx.x] = val;
}

__global__ __launch_bounds__(128) void scanB_k(int* __restrict__ bsums, int nb) {
    __shared__ int sh[128];
    const int tid = threadIdx.x;
    const int v = (tid < nb) ? bsums[tid] : 0;
    sh[tid] = v;
    __syncthreads();
    int val = v;
    for (int off = 1; off < 128; off <<= 1) {
        const int t = (tid >= off) ? sh[tid - off] : 0;
        __syncthreads();
        val += t;
        sh[tid] = val;
        __syncthreads();
    }
    if (tid < nb) bsums[tid] = val - v;
}

__global__ __launch_bounds__(1024) void scanC_k(int* __restrict__ offs,
                                                const int* __restrict__ bsums,
                                                int* __restrict__ pos) {
    const int i = blockIdx.x * 1024 + threadIdx.x;
    if (i < M_TOT) {
        const int val = offs[i] + bsums[blockIdx.x];
        offs[i] = val;
        pos[i] = val;
    }
    if (i == 0) offs[M_TOT] = E_TOT;
}

// srcs as ushort: halves the random-scatter write amplification
__global__ void fill_all_k(const int* __restrict__ ei, int* __restrict__ pos,
                           ushort* __restrict__ srcs) {
    const int e = blockIdx.x * 256 + threadIdx.x;
    if (e < E_TOT) {
        const int hop = e / N_EDGES;
        const int idx = e - hop * N_EDGES;
        const int s = ei[(size_t)hop * 2 * N_EDGES + idx];
        const int d = ei[(size_t)hop * 2 * N_EDGES + N_EDGES + idx];
        const int p = atomicAdd(&pos[hop * N_NODES + d], 1);
        srcs[p] = (ushort)s;
    }
}

// ---------------- GIN aggregation (bf16 in / bf16 out) ----------------
// one wave per node; lane l covers cols 2l, 2l+1 (uint = bf16x2, 256B rows)
__global__ __launch_bounds__(256) void agg_k(const ushort* __restrict__ x,
                                             const int* __restrict__ offs,
                                             const ushort* __restrict__ srcs,
                                             const float* __restrict__ epsk,
                                             ushort* __restrict__ z) {
    const int node = blockIdx.x * 4 + (threadIdx.x >> 6);
    if (node >= N_NODES) return;
    const int lane = threadIdx.x & 63;
    const float a = 1.0f + epsk[0];
    const uint* x2 = (const uint*)x;

    const uint xv = x2[(size_t)node * 64 + lane];
    float ax = a * bf2f((ushort)(xv & 0xffff));
    float ay = a * bf2f((ushort)(xv >> 16));
    float bx = 0.f, by = 0.f, cx = 0.f, cy = 0.f, dx = 0.f, dy = 0.f;

    const int beg = offs[node], end = offs[node + 1];
    int i = beg;
    for (; i + 3 < end; i += 4) {
        const int s0 = srcs[i], s1 = srcs[i + 1], s2 = srcs[i + 2], s3 = srcs[i + 3];
        const uint v0 = x2[(size_t)s0 * 64 + lane];
        const uint v1 = x2[(size_t)s1 * 64 + lane];
        const uint v2 = x2[(size_t)s2 * 64 + lane];
        const uint v3 = x2[(size_t)s3 * 64 + lane];
        ax += bf2f((ushort)(v0 & 0xffff)); ay += bf2f((ushort)(v0 >> 16));
        bx += bf2f((ushort)(v1 & 0xffff)); by += bf2f((ushort)(v1 >> 16));
        cx += bf2f((ushort)(v2 & 0xffff)); cy += bf2f((ushort)(v2 >> 16));
        dx += bf2f((ushort)(v3 & 0xffff)); dy += bf2f((ushort)(v3 >> 16));
    }
    for (; i < end; ++i) {
        const int s = srcs[i];
        const uint v = x2[(size_t)s * 64 + lane];
        ax += bf2f((ushort)(v & 0xffff)); ay += bf2f((ushort)(v >> 16));
    }
    const float ox = (ax + bx) + (cx + dx);
    const float oy = (ay + by) + (cy + dy);
    ((uint*)z)[(size_t)node * 64 + lane] = (uint)f2bf(ox) | ((uint)f2bf(oy) << 16);
}

// ---------------- driver ----------------
extern "C" void kernel_launch(void* const* d_in, const int* in_sizes, int n_in,
                              void* d_out, int out_size, void* d_ws, size_t ws_size,
                              hipStream_t stream)
{
    const float* xs  = (const float*)d_in[0];
    const int*   ei  = (const int*)d_in[1];
    const float* lW1 = (const float*)d_in[2];
    const float* lb1 = (const float*)d_in[3];
    const float* lg  = (const float*)d_in[4];
    const float* lbt = (const float*)d_in[5];
    const float* lm  = (const float*)d_in[6];
    const float* lv  = (const float*)d_in[7];
    const float* lW2 = (const float*)d_in[8];
    const float* lb2 = (const float*)d_in[9];
    const float* eps = (const float*)d_in[10];
    const float* cW1 = (const float*)d_in[11];
    const float* cb1 = (const float*)d_in[12];
    const float* cg  = (const float*)d_in[13];
    const float* cbt = (const float*)d_in[14];
    const float* cm  = (const float*)d_in[15];
    const float* cv  = (const float*)d_in[16];
    const float* cW2 = (const float*)d_in[17];
    const float* cb2 = (const float*)d_in[18];
    float* out = (float*)d_out;

    char* ws = (char*)d_ws;
    ushort* xb   = (ushort*)ws;  ws += (size_t)N_NODES * D * sizeof(ushort);
    ushort* zb   = (ushort*)ws;  ws += (size_t)N_NODES * D * sizeof(ushort);
    ushort* Wt   = (ushort*)ws;  ws += (size_t)8 * D * D * sizeof(ushort);
    float*  scof = (float*)ws;   ws += (size_t)4 * 2 * D * sizeof(float);
    int* counts  = (int*)ws;     ws += (size_t)(M_TOT + 64) * sizeof(int);
    int* offs    = (int*)ws;     ws += (size_t)(M_TOT + 64) * sizeof(int);
    int* pos     = (int*)ws;     ws += (size_t)(M_TOT + 64) * sizeof(int);
    int* bsums   = (int*)ws;     ws += 128 * sizeof(int);
    ushort* srcs = (ushort*)ws;

    const int gemmGrid = (N_NODES + 63) / 64;            // 469
    const int edgeGrid = (E_TOT + 255) / 256;
    const int convGrid = (N_NODES * D / 4 + 255) / 256;  // 3750

    // weight/BN prep
    prep_w_k<<<8, 256, 0, stream>>>(lW1, lW2, cW1, cW2, Wt);
    scof_k<<<1, 512, 0, stream>>>(lb1, lg, lbt, lm, lv, cb1, cg, cbt, cm, cv, scof);

    // CSR for all 3 hops
    hipMemsetAsync(counts, 0, M_TOT * sizeof(int), stream);
    count_all_k<<<edgeGrid, 256, 0, stream>>>(ei, counts);
    scanA_k<<<SCAN_NBLK, 1024, 0, stream>>>(counts, offs, bsums);
    scanB_k<<<1, 128, 0, stream>>>(bsums, SCAN_NBLK);
    scanC_k<<<SCAN_NBLK, 1024, 0, stream>>>(offs, bsums, pos);
    fill_all_k<<<edgeGrid, 256, 0, stream>>>(ei, pos, srcs);

    // lin layer
    conv_k<<<convGrid, 256, 0, stream>>>(xs, xb, N_NODES * D / 4);
    layer_k<0><<<gemmGrid, 256, 0, stream>>>(xb, Wt, Wt + D * D, scof, lb2, out, N_NODES);

    for (int k = 0; k < H; ++k) {
        conv_k<<<convGrid, 256, 0, stream>>>(xs + (size_t)(k + 1) * N_NODES * D, xb,
                                             N_NODES * D / 4);
        agg_k<<<(N_NODES + 3) / 4, 256, 0, stream>>>(xb, offs + (size_t)k * N_NODES,
                                                     srcs, eps + k, zb);
        layer_k<1><<<gemmGrid, 256, 0, stream>>>(zb,
                                                 Wt + (size_t)(2 + 2 * k) * D * D,
                                                 Wt + (size_t)(3 + 2 * k) * D * D,
                                                 scof + (size_t)(k + 1) * 256,
                                                 cb2 + (size_t)k * D, out, N_NODES);
    }
}

// Round 4
// 237.339 us; speedup vs baseline: 2.5549x; 1.4030x over previous
//
#include <hip/hip_runtime.h>

#define N_NODES 30000
#define N_EDGES 480000
#define D 128
#define H 3
#define BN_EPS 1e-5f
#define M_TOT (H * N_NODES)
#define E_TOT (H * N_EDGES)

#define NCH 64                       // chunks per hop
#define CHE (N_EDGES / NCH)          // 7500 edges per chunk
#define NBKT 512                     // dst buckets per hop (dst>>6)
#define NBKT_TOT (H * NBKT)          // 1536
#define CELLS (NBKT_TOT * NCH)       // 98304 = 96 * 1024 exactly
#define SCAN_NBLK (CELLS / 1024)     // 96

typedef __attribute__((ext_vector_type(8))) short short8v;   // 8 x bf16
typedef __attribute__((ext_vector_type(4))) float f32x4;     // MFMA accumulator

__device__ __forceinline__ ushort f2bf(float f) {            // RNE f32 -> bf16
    uint u = __float_as_uint(f);
    u += 0x7fffu + ((u >> 16) & 1u);
    return (ushort)(u >> 16);
}
__device__ __forceinline__ float bf2f(ushort b) {
    return __uint_as_float(((uint)b) << 16);
}

// ---------------- prep: f32 slice -> bf16 ----------------
__global__ __launch_bounds__(256) void conv_k(const float* __restrict__ src,
                                              ushort* __restrict__ dst, int n4) {
    const int i = blockIdx.x * 256 + threadIdx.x;
    if (i < n4) {
        const float4 v = ((const float4*)src)[i];
        ushort4 o;
        o.x = f2bf(v.x); o.y = f2bf(v.y); o.z = f2bf(v.z); o.w = f2bf(v.w);
        ((ushort4*)dst)[i] = o;
    }
}

// ---------------- prep: transpose+convert the 8 weight matrices -------------
__global__ __launch_bounds__(256) void prep_w_k(
    const float* __restrict__ lW1, const float* __restrict__ lW2,
    const float* __restrict__ cW1, const float* __restrict__ cW2,
    ushort* __restrict__ Wt)
{
    const int mat = blockIdx.x;
    const float* src;
    if (mat == 0) src = lW1;
    else if (mat == 1) src = lW2;
    else {
        const int k = (mat - 2) >> 1;
        src = ((mat & 1) == 0 ? cW1 : cW2) + (size_t)k * D * D;
    }
    ushort* dst = Wt + (size_t)mat * D * D;
    for (int idx = threadIdx.x; idx < D * D; idx += 256) {
        const int n = idx >> 7, k = idx & 127;
        dst[idx] = f2bf(src[k * D + n]);
    }
}

// ---------------- prep: fold BN into scale/offset per layer ----------------
__global__ __launch_bounds__(512) void scof_k(
    const float* __restrict__ lb1, const float* __restrict__ lg,
    const float* __restrict__ lbt, const float* __restrict__ lm,
    const float* __restrict__ lv,
    const float* __restrict__ cb1, const float* __restrict__ cg,
    const float* __restrict__ cbt, const float* __restrict__ cm,
    const float* __restrict__ cv, float* __restrict__ scof)
{
    const int tid = threadIdx.x;
    const int L = tid >> 7, c = tid & 127;
    float g, v, b, m, bt;
    if (L == 0) { g = lg[c]; v = lv[c]; b = lb1[c]; m = lm[c]; bt = lbt[c]; }
    else {
        const int k = L - 1;
        g = cg[k * D + c]; v = cv[k * D + c]; b = cb1[k * D + c];
        m = cm[k * D + c]; bt = cbt[k * D + c];
    }
    const float s = g * rsqrtf(v + BN_EPS);
    scof[L * 256 + c] = s;
    scof[L * 256 + 128 + c] = (b - m) * s + bt;
}

// ---------------- Fused MFMA layer (as round 3, verified) ----------------
#define LW 136

template <int ACC>
__global__ __launch_bounds__(256) void layer_k(
    const ushort* __restrict__ X, const ushort* __restrict__ W1t,
    const ushort* __restrict__ W2t, const float* __restrict__ scof,
    const float* __restrict__ b2, float* __restrict__ out, int nrows)
{
    __shared__ ushort Xs[64 * LW];
    __shared__ ushort Ws[128 * LW];
    const int tid = threadIdx.x;
    const int wave = tid >> 6, lane = tid & 63;
    const int m16 = lane & 15, kq = lane >> 4;
    const int row0 = blockIdx.x * 64;

    for (int f = tid; f < 2048; f += 256) {
        const int r = f >> 5, c8 = f & 31;
        ushort4 v = make_ushort4(0, 0, 0, 0);
        const int gr = row0 + r;
        if (gr < nrows) v = *(const ushort4*)(X + (size_t)gr * D + c8 * 4);
        *(ushort4*)(&Xs[r * LW + c8 * 4]) = v;
    }
    for (int f = tid; f < 4096; f += 256) {
        const int n = f >> 5, c8 = f & 31;
        *(ushort4*)(&Ws[n * LW + c8 * 4]) = *(const ushort4*)(W1t + n * D + c8 * 4);
    }
    __syncthreads();

    const int arow = wave * 16 + m16;
    f32x4 acc[8];
#pragma unroll
    for (int t = 0; t < 8; ++t) acc[t] = (f32x4){0.f, 0.f, 0.f, 0.f};

#pragma unroll
    for (int kk = 0; kk < 4; ++kk) {
        const short8v a = *(const short8v*)(&Xs[arow * LW + kk * 32 + kq * 8]);
#pragma unroll
        for (int t = 0; t < 8; ++t) {
            const short8v b = *(const short8v*)(&Ws[(t * 16 + m16) * LW + kk * 32 + kq * 8]);
            acc[t] = __builtin_amdgcn_mfma_f32_16x16x32_bf16(a, b, acc[t], 0, 0, 0);
        }
    }
    __syncthreads();

#pragma unroll
    for (int t = 0; t < 8; ++t) {
        const int n = t * 16 + m16;
        const float sc = scof[n], of = scof[128 + n];
#pragma unroll
        for (int r = 0; r < 4; ++r) {
            const int m = wave * 16 + kq * 4 + r;
            Xs[m * LW + n] = f2bf(fmaxf(acc[t][r] * sc + of, 0.f));
        }
    }
    for (int f = tid; f < 4096; f += 256) {
        const int n = f >> 5, c8 = f & 31;
        *(ushort4*)(&Ws[n * LW + c8 * 4]) = *(const ushort4*)(W2t + n * D + c8 * 4);
    }
    __syncthreads();

    f32x4 acc2[8];
#pragma unroll
    for (int t = 0; t < 8; ++t) acc2[t] = (f32x4){0.f, 0.f, 0.f, 0.f};

#pragma unroll
    for (int kk = 0; kk < 4; ++kk) {
        const short8v a = *(const short8v*)(&Xs[arow * LW + kk * 32 + kq * 8]);
#pragma unroll
        for (int t = 0; t < 8; ++t) {
            const short8v b = *(const short8v*)(&Ws[(t * 16 + m16) * LW + kk * 32 + kq * 8]);
            acc2[t] = __builtin_amdgcn_mfma_f32_16x16x32_bf16(a, b, acc2[t], 0, 0, 0);
        }
    }

#pragma unroll
    for (int t = 0; t < 8; ++t) {
        const int n = t * 16 + m16;
        const float bb = b2[n];
#pragma unroll
        for (int r = 0; r < 4; ++r) {
            const int gr = row0 + wave * 16 + kq * 4 + r;
            if (gr < nrows) {
                float* p = out + (size_t)gr * D + n;
                float v = acc2[t][r] + bb;
                if (ACC) v += *p;
                *p = v;
            }
        }
    }
}

// ---------------- CSR build: deterministic two-pass multisplit -------------
// pass 1: per-chunk LDS histogram of dst>>6 -> cnts[bucket][chunk]
__global__ __launch_bounds__(256) void bincount_k(const int* __restrict__ ei,
                                                  int* __restrict__ cnts) {
    __shared__ int hc[NBKT];
    const int chunk = blockIdx.x;        // 0..191
    const int hop = chunk >> 6, c = chunk & 63;
    for (int i = threadIdx.x; i < NBKT; i += 256) hc[i] = 0;
    __syncthreads();
    const int* dstp = ei + (size_t)hop * 2 * N_EDGES + N_EDGES + c * CHE;
    for (int i = threadIdx.x; i < CHE; i += 256)
        atomicAdd(&hc[dstp[i] >> 6], 1);
    __syncthreads();
    for (int b = threadIdx.x; b < NBKT; b += 256)
        cnts[((hop * NBKT + b) << 6) | c] = hc[b];
}

// exclusive scan of the 98304 cells (3 phases)
__global__ __launch_bounds__(1024) void scanA_k(int* __restrict__ cnts,
                                                int* __restrict__ bsums) {
    __shared__ int sh[1024];
    const int tid = threadIdx.x;
    const int i = blockIdx.x * 1024 + tid;
    const int v = cnts[i];
    sh[tid] = v;
    __syncthreads();
    int val = v;
    for (int off = 1; off < 1024; off <<= 1) {
        const int t = (tid >= off) ? sh[tid - off] : 0;
        __syncthreads();
        val += t;
        sh[tid] = val;
        __syncthreads();
    }
    cnts[i] = val - v;
    if (tid == 1023) bsums[blockIdx.x] = val;
}

__global__ __launch_bounds__(128) void scanB_k(int* __restrict__ bsums, int nb) {
    __shared__ int sh[128];
    const int tid = threadIdx.x;
    const int v = (tid < nb) ? bsums[tid] : 0;
    sh[tid] = v;
    __syncthreads();
    int val = v;
    for (int off = 1; off < 128; off <<= 1) {
        const int t = (tid >= off) ? sh[tid - off] : 0;
        __syncthreads();
        val += t;
        sh[tid] = val;
        __syncthreads();
    }
    if (tid < nb) bsums[tid] = val - v;
}

__global__ __launch_bounds__(1024) void scanC_k(int* __restrict__ cnts,
                                                const int* __restrict__ bsums,
                                                int* __restrict__ offs) {
    const int i = blockIdx.x * 1024 + threadIdx.x;
    cnts[i] += bsums[blockIdx.x];
    if (i == 0) offs[M_TOT] = E_TOT;     // CSR sentinel
}

// pass 2: place edges into block-private sequential windows (no global atomics)
__global__ __launch_bounds__(256) void binplace_k(const int* __restrict__ ei,
                                                  const int* __restrict__ cnts,
                                                  uint* __restrict__ binned) {
    __shared__ int cur[NBKT];
    const int chunk = blockIdx.x;
    const int hop = chunk >> 6, c = chunk & 63;
    for (int b = threadIdx.x; b < NBKT; b += 256)
        cur[b] = cnts[((hop * NBKT + b) << 6) | c];
    __syncthreads();
    const int* srcp = ei + (size_t)hop * 2 * N_EDGES + c * CHE;
    const int* dstp = srcp + N_EDGES;
    for (int i = threadIdx.x; i < CHE; i += 256) {
        const int s = srcp[i], d = dstp[i];
        const int slot = atomicAdd(&cur[d >> 6], 1);
        binned[slot] = ((uint)(d & 63) << 16) | (uint)s;
    }
}

// per bucket: local CSR (hist + scan) in LDS, coalesced srcs write + offs
__global__ __launch_bounds__(256) void cat_k(const uint* __restrict__ binned,
                                             const int* __restrict__ cnts,
                                             int* __restrict__ offs,
                                             ushort* __restrict__ srcs) {
    const int B = blockIdx.x;                 // hop*512 + bucket
    const int hop = B >> 9, bb = B & 511;
    const int dstbase = bb << 6;
    if (dstbase >= N_NODES) return;           // empty tail buckets
    const int bB = cnts[B << 6];
    const int bE = (B == NBKT_TOT - 1) ? E_TOT : cnts[(B + 1) << 6];
    const int cnt = bE - bB;

    __shared__ uint ent[2048];
    __shared__ ushort stg[2048];
    __shared__ int hist[64], cur[64];

    for (int d = threadIdx.x; d < 64; d += 256) hist[d] = 0;
    __syncthreads();
    for (int i = threadIdx.x; i < cnt; i += 256) {
        const uint e = binned[bB + i];
        ent[i] = e;
        atomicAdd(&hist[e >> 16], 1);
    }
    __syncthreads();
    if (threadIdx.x < 64) {                   // wave-0 exclusive scan of 64
        const int v = hist[threadIdx.x];
        int x = v;
        for (int off = 1; off < 64; off <<= 1) {
            const int t = __shfl_up(x, off, 64);
            if (threadIdx.x >= off) x += t;
        }
        cur[threadIdx.x] = x - v;
        const int gd = dstbase + threadIdx.x;
        if (gd < N_NODES) offs[hop * N_NODES + gd] = bB + x - v;
    }
    __syncthreads();
    for (int i = threadIdx.x; i < cnt; i += 256) {
        const uint e = ent[i];
        const int lp = atomicAdd(&cur[e >> 16], 1);
        stg[lp] = (ushort)(e & 0xffffu);
    }
    __syncthreads();
    for (int i = threadIdx.x; i < cnt; i += 256)
        srcs[bB + i] = stg[i];
}

// ---------------- GIN aggregation (bf16, 8-way unrolled gather) -------------
__global__ __launch_bounds__(256) void agg_k(const ushort* __restrict__ x,
                                             const int* __restrict__ offs,
                                             const ushort* __restrict__ srcs,
                                             const float* __restrict__ epsk,
                                             ushort* __restrict__ z) {
    const int node = blockIdx.x * 4 + (threadIdx.x >> 6);
    if (node >= N_NODES) return;
    const int lane = threadIdx.x & 63;
    const float a = 1.0f + epsk[0];
    const uint* x2 = (const uint*)x;

    const uint xv = x2[(size_t)node * 64 + lane];
    float accx[8], accy[8];
#pragma unroll
    for (int u = 0; u < 8; ++u) { accx[u] = 0.f; accy[u] = 0.f; }
    accx[0] = a * bf2f((ushort)(xv & 0xffff));
    accy[0] = a * bf2f((ushort)(xv >> 16));

    const int beg = offs[node], end = offs[node + 1];
    int i = beg;
    for (; i + 8 <= end; i += 8) {
        uint v[8];
#pragma unroll
        for (int u = 0; u < 8; ++u) v[u] = x2[(size_t)srcs[i + u] * 64 + lane];
#pragma unroll
        for (int u = 0; u < 8; ++u) {
            accx[u] += bf2f((ushort)(v[u] & 0xffff));
            accy[u] += bf2f((ushort)(v[u] >> 16));
        }
    }
    for (; i < end; ++i) {
        const uint v = x2[(size_t)srcs[i] * 64 + lane];
        accx[7] += bf2f((ushort)(v & 0xffff));
        accy[7] += bf2f((ushort)(v >> 16));
    }
    const float ox = ((accx[0] + accx[1]) + (accx[2] + accx[3])) +
                     ((accx[4] + accx[5]) + (accx[6] + accx[7]));
    const float oy = ((accy[0] + accy[1]) + (accy[2] + accy[3])) +
                     ((accy[4] + accy[5]) + (accy[6] + accy[7]));
    ((uint*)z)[(size_t)node * 64 + lane] = (uint)f2bf(ox) | ((uint)f2bf(oy) << 16);
}

// ---------------- driver ----------------
extern "C" void kernel_launch(void* const* d_in, const int* in_sizes, int n_in,
                              void* d_out, int out_size, void* d_ws, size_t ws_size,
                              hipStream_t stream)
{
    const float* xs  = (const float*)d_in[0];
    const int*   ei  = (const int*)d_in[1];
    const float* lW1 = (const float*)d_in[2];
    const float* lb1 = (const float*)d_in[3];
    const float* lg  = (const float*)d_in[4];
    const float* lbt = (const float*)d_in[5];
    const float* lm  = (const float*)d_in[6];
    const float* lv  = (const float*)d_in[7];
    const float* lW2 = (const float*)d_in[8];
    const float* lb2 = (const float*)d_in[9];
    const float* eps = (const float*)d_in[10];
    const float* cW1 = (const float*)d_in[11];
    const float* cb1 = (const float*)d_in[12];
    const float* cg  = (const float*)d_in[13];
    const float* cbt = (const float*)d_in[14];
    const float* cm  = (const float*)d_in[15];
    const float* cv  = (const float*)d_in[16];
    const float* cW2 = (const float*)d_in[17];
    const float* cb2 = (const float*)d_in[18];
    float* out = (float*)d_out;

    char* ws = (char*)d_ws;
    ushort* xb   = (ushort*)ws;  ws += (size_t)N_NODES * D * sizeof(ushort);
    ushort* zb   = (ushort*)ws;  ws += (size_t)N_NODES * D * sizeof(ushort);
    ushort* Wt   = (ushort*)ws;  ws += (size_t)8 * D * D * sizeof(ushort);
    float*  scof = (float*)ws;   ws += (size_t)4 * 2 * D * sizeof(float);
    int* cnts    = (int*)ws;     ws += (size_t)CELLS * sizeof(int);
    int* bsums   = (int*)ws;     ws += 128 * sizeof(int);
    int* offs    = (int*)ws;     ws += (size_t)(M_TOT + 64) * sizeof(int);
    uint* binned = (uint*)ws;    ws += (size_t)E_TOT * sizeof(uint);
    ushort* srcs = (ushort*)ws;

    const int gemmGrid = (N_NODES + 63) / 64;
    const int convGrid = (N_NODES * D / 4 + 255) / 256;

    // weight/BN prep
    prep_w_k<<<8, 256, 0, stream>>>(lW1, lW2, cW1, cW2, Wt);
    scof_k<<<1, 512, 0, stream>>>(lb1, lg, lbt, lm, lv, cb1, cg, cbt, cm, cv, scof);

    // CSR via multisplit (no global atomics, no memset)
    bincount_k<<<H * NCH, 256, 0, stream>>>(ei, cnts);
    scanA_k<<<SCAN_NBLK, 1024, 0, stream>>>(cnts, bsums);
    scanB_k<<<1, 128, 0, stream>>>(bsums, SCAN_NBLK);
    scanC_k<<<SCAN_NBLK, 1024, 0, stream>>>(cnts, bsums, offs);
    binplace_k<<<H * NCH, 256, 0, stream>>>(ei, cnts, binned);
    cat_k<<<NBKT_TOT, 256, 0, stream>>>(binned, cnts, offs, srcs);

    // lin layer
    conv_k<<<convGrid, 256, 0, stream>>>(xs, xb, N_NODES * D / 4);
    layer_k<0><<<gemmGrid, 256, 0, stream>>>(xb, Wt, Wt + D * D, scof, lb2, out, N_NODES);

    for (int k = 0; k < H; ++k) {
        conv_k<<<convGrid, 256, 0, stream>>>(xs + (size_t)(k + 1) * N_NODES * D, xb,
                                             N_NODES * D / 4);
        agg_k<<<(N_NODES + 3) / 4, 256, 0, stream>>>(xb, offs + (size_t)k * N_NODES,
                                                     srcs, eps + k, zb);
        layer_k<1><<<gemmGrid, 256, 0, stream>>>(zb,
                                                 Wt + (size_t)(2 + 2 * k) * D * D,
                                                 Wt + (size_t)(3 + 2 * k) * D * D,
                                                 scof + (size_t)(k + 1) * 256,
                                                 cb2 + (size_t)k * D, out, N_NODES);
    }
}

// Round 5
// 192.462 us; speedup vs baseline: 3.1507x; 1.2332x over previous
//
#include <hip/hip_runtime.h>

#define N_NODES 30000
#define N_EDGES 480000
#define D 128
#define H 3
#define BN_EPS 1e-5f
#define M_TOT (H * N_NODES)
#define E_TOT (H * N_EDGES)

#define NCH 64                       // chunks per hop
#define CHE (N_EDGES / NCH)          // 7500 edges per chunk
#define NBKT 512                     // dst buckets per hop (dst>>6)
#define NBKT_TOT (H * NBKT)          // 1536
#define CELLS (NBKT_TOT * NCH)       // 98304 = 96 * 1024
#define SCAN_NBLK (CELLS / 1024)     // 96

typedef __attribute__((ext_vector_type(8))) short short8v;   // 8 x bf16
typedef __attribute__((ext_vector_type(4))) float f32x4;     // MFMA accumulator

__device__ __forceinline__ ushort f2bf(float f) {            // RNE f32 -> bf16
    uint u = __float_as_uint(f);
    u += 0x7fffu + ((u >> 16) & 1u);
    return (ushort)(u >> 16);
}
__device__ __forceinline__ float bf2f(ushort b) {
    return __uint_as_float(((uint)b) << 16);
}

// ---------------- prep: all 4 f32 slices -> bf16 (one launch) ----------------
__global__ __launch_bounds__(256) void conv_k(const float* __restrict__ src,
                                              ushort* __restrict__ dst, int n4) {
    const int i = blockIdx.x * 256 + threadIdx.x;
    if (i < n4) {
        const float4 v = ((const float4*)src)[i];
        ushort4 o;
        o.x = f2bf(v.x); o.y = f2bf(v.y); o.z = f2bf(v.z); o.w = f2bf(v.w);
        ((ushort4*)dst)[i] = o;
    }
}

// ---------------- prep: transpose+convert the 8 weight matrices -------------
__global__ __launch_bounds__(256) void prep_w_k(
    const float* __restrict__ lW1, const float* __restrict__ lW2,
    const float* __restrict__ cW1, const float* __restrict__ cW2,
    ushort* __restrict__ Wt)
{
    const int mat = blockIdx.x;
    const float* src;
    if (mat == 0) src = lW1;
    else if (mat == 1) src = lW2;
    else {
        const int k = (mat - 2) >> 1;
        src = ((mat & 1) == 0 ? cW1 : cW2) + (size_t)k * D * D;
    }
    ushort* dst = Wt + (size_t)mat * D * D;
    for (int idx = threadIdx.x; idx < D * D; idx += 256) {
        const int n = idx >> 7, k = idx & 127;
        dst[idx] = f2bf(src[k * D + n]);
    }
}

// ---------------- prep: BN scale/offset per layer + total output bias -------
__global__ __launch_bounds__(512) void scof_k(
    const float* __restrict__ lb1, const float* __restrict__ lg,
    const float* __restrict__ lbt, const float* __restrict__ lm,
    const float* __restrict__ lv,
    const float* __restrict__ cb1, const float* __restrict__ cg,
    const float* __restrict__ cbt, const float* __restrict__ cm,
    const float* __restrict__ cv,
    const float* __restrict__ lb2, const float* __restrict__ cb2,
    float* __restrict__ scof)
{
    const int tid = threadIdx.x;
    const int L = tid >> 7, c = tid & 127;
    float g, v, b, m, bt;
    if (L == 0) { g = lg[c]; v = lv[c]; b = lb1[c]; m = lm[c]; bt = lbt[c]; }
    else {
        const int k = L - 1;
        g = cg[k * D + c]; v = cv[k * D + c]; b = cb1[k * D + c];
        m = cm[k * D + c]; bt = cbt[k * D + c];
    }
    const float s = g * rsqrtf(v + BN_EPS);
    scof[L * 256 + c] = s;
    scof[L * 256 + 128 + c] = (b - m) * s + bt;
    if (tid < 128) {                       // btot = lb2 + sum_k cb2[k]
        float t = lb2[tid];
        for (int k = 0; k < H; ++k) t += cb2[k * D + tid];
        scof[1024 + tid] = t;
    }
}

// ---------------- Fused 4-layer MLP: out = sum_L relu(bn(X_L@W1+b1))@W2 -----
// One block = 64 rows; accO chains as MFMA C across all 4 layers; single
// f32 write of out. X_0 = xball slice 0; X_{1..3} = zb[hop].
#define LW 136

__global__ __launch_bounds__(256) void fused4_k(
    const ushort* __restrict__ xball, const ushort* __restrict__ zb,
    const ushort* __restrict__ Wt, const float* __restrict__ scof,
    float* __restrict__ out)
{
    __shared__ ushort Xs[64 * LW];
    __shared__ ushort Ws[128 * LW];
    const int tid = threadIdx.x;
    const int wave = tid >> 6, lane = tid & 63;
    const int m16 = lane & 15, kq = lane >> 4;
    const int row0 = blockIdx.x * 64;
    const int arow = wave * 16 + m16;

    f32x4 accO[8];
#pragma unroll
    for (int t = 0; t < 8; ++t) accO[t] = (f32x4){0.f, 0.f, 0.f, 0.f};

    for (int L = 0; L < 4; ++L) {
        const ushort* X = (L == 0) ? xball : zb + (size_t)(L - 1) * N_NODES * D;
        const ushort* W1t = Wt + (size_t)(2 * L) * D * D;
        const ushort* W2t = W1t + D * D;
        const float* scL = scof + L * 256;

        if (L) __syncthreads();     // prior layer's GEMM2 readers done
        for (int f = tid; f < 2048; f += 256) {
            const int r = f >> 5, c8 = (f & 31) << 2;
            ushort4 v = make_ushort4(0, 0, 0, 0);
            const int gr = row0 + r;
            if (gr < N_NODES) v = *(const ushort4*)(X + (size_t)gr * D + c8);
            *(ushort4*)(&Xs[r * LW + c8]) = v;
        }
        for (int f = tid; f < 4096; f += 256) {
            const int n = f >> 5, c8 = (f & 31) << 2;
            *(ushort4*)(&Ws[n * LW + c8]) = *(const ushort4*)(W1t + n * D + c8);
        }
        __syncthreads();

        f32x4 acc[8];
#pragma unroll
        for (int t = 0; t < 8; ++t) acc[t] = (f32x4){0.f, 0.f, 0.f, 0.f};
#pragma unroll
        for (int kk = 0; kk < 4; ++kk) {
            const short8v a = *(const short8v*)(&Xs[arow * LW + kk * 32 + kq * 8]);
#pragma unroll
            for (int t = 0; t < 8; ++t) {
                const short8v b = *(const short8v*)(&Ws[(t * 16 + m16) * LW + kk * 32 + kq * 8]);
                acc[t] = __builtin_amdgcn_mfma_f32_16x16x32_bf16(a, b, acc[t], 0, 0, 0);
            }
        }
        __syncthreads();            // GEMM1 readers done before Xs/Ws overwrite

        // epilogue 1: h = relu(bn(.)) -> bf16 back into Xs; restage Ws = W2
#pragma unroll
        for (int t = 0; t < 8; ++t) {
            const int n = t * 16 + m16;
            const float sc = scL[n], of = scL[128 + n];
#pragma unroll
            for (int r = 0; r < 4; ++r) {
                const int m = wave * 16 + kq * 4 + r;
                Xs[m * LW + n] = f2bf(fmaxf(acc[t][r] * sc + of, 0.f));
            }
        }
        for (int f = tid; f < 4096; f += 256) {
            const int n = f >> 5, c8 = (f & 31) << 2;
            *(ushort4*)(&Ws[n * LW + c8]) = *(const ushort4*)(W2t + n * D + c8);
        }
        __syncthreads();

        // GEMM2 accumulates straight into accO (C-in chaining across layers)
#pragma unroll
        for (int kk = 0; kk < 4; ++kk) {
            const short8v a = *(const short8v*)(&Xs[arow * LW + kk * 32 + kq * 8]);
#pragma unroll
            for (int t = 0; t < 8; ++t) {
                const short8v b = *(const short8v*)(&Ws[(t * 16 + m16) * LW + kk * 32 + kq * 8]);
                accO[t] = __builtin_amdgcn_mfma_f32_16x16x32_bf16(a, b, accO[t], 0, 0, 0);
            }
        }
    }

    const float* btot = scof + 1024;
#pragma unroll
    for (int t = 0; t < 8; ++t) {
        const int n = t * 16 + m16;
        const float bb = btot[n];
#pragma unroll
        for (int r = 0; r < 4; ++r) {
            const int gr = row0 + wave * 16 + kq * 4 + r;
            if (gr < N_NODES) out[(size_t)gr * D + n] = accO[t][r] + bb;
        }
    }
}

// ---------------- CSR build: deterministic two-pass multisplit -------------
__global__ __launch_bounds__(256) void bincount_k(const int* __restrict__ ei,
                                                  int* __restrict__ cnts) {
    __shared__ int hc[NBKT];
    const int chunk = blockIdx.x;
    const int hop = chunk >> 6, c = chunk & 63;
    for (int i = threadIdx.x; i < NBKT; i += 256) hc[i] = 0;
    __syncthreads();
    const int* dstp = ei + (size_t)hop * 2 * N_EDGES + N_EDGES + c * CHE;
    for (int i = threadIdx.x; i < CHE; i += 256)
        atomicAdd(&hc[dstp[i] >> 6], 1);
    __syncthreads();
    for (int b = threadIdx.x; b < NBKT; b += 256)
        cnts[((hop * NBKT + b) << 6) | c] = hc[b];
}

__global__ __launch_bounds__(1024) void scanA_k(int* __restrict__ cnts,
                                                int* __restrict__ bsums) {
    __shared__ int sh[1024];
    const int tid = threadIdx.x;
    const int i = blockIdx.x * 1024 + tid;
    const int v = cnts[i];
    sh[tid] = v;
    __syncthreads();
    int val = v;
    for (int off = 1; off < 1024; off <<= 1) {
        const int t = (tid >= off) ? sh[tid - off] : 0;
        __syncthreads();
        val += t;
        sh[tid] = val;
        __syncthreads();
    }
    cnts[i] = val - v;
    if (tid == 1023) bsums[blockIdx.x] = val;
}

__global__ __launch_bounds__(128) void scanB_k(int* __restrict__ bsums, int nb) {
    __shared__ int sh[128];
    const int tid = threadIdx.x;
    const int v = (tid < nb) ? bsums[tid] : 0;
    sh[tid] = v;
    __syncthreads();
    int val = v;
    for (int off = 1; off < 128; off <<= 1) {
        const int t = (tid >= off) ? sh[tid - off] : 0;
        __syncthreads();
        val += t;
        sh[tid] = val;
        __syncthreads();
    }
    if (tid < nb) bsums[tid] = val - v;
}

__global__ __launch_bounds__(1024) void scanC_k(int* __restrict__ cnts,
                                                const int* __restrict__ bsums,
                                                int* __restrict__ offs) {
    const int i = blockIdx.x * 1024 + threadIdx.x;
    cnts[i] += bsums[blockIdx.x];
    if (i == 0) offs[M_TOT] = E_TOT;
}

__global__ __launch_bounds__(256) void binplace_k(const int* __restrict__ ei,
                                                  const int* __restrict__ cnts,
                                                  uint* __restrict__ binned) {
    __shared__ int cur[NBKT];
    const int chunk = blockIdx.x;
    const int hop = chunk >> 6, c = chunk & 63;
    for (int b = threadIdx.x; b < NBKT; b += 256)
        cur[b] = cnts[((hop * NBKT + b) << 6) | c];
    __syncthreads();
    const int* srcp = ei + (size_t)hop * 2 * N_EDGES + c * CHE;
    const int* dstp = srcp + N_EDGES;
    for (int i = threadIdx.x; i < CHE; i += 256) {
        const int s = srcp[i], d = dstp[i];
        const int slot = atomicAdd(&cur[d >> 6], 1);
        binned[slot] = ((uint)(d & 63) << 16) | (uint)s;
    }
}

__global__ __launch_bounds__(256) void cat_k(const uint* __restrict__ binned,
                                             const int* __restrict__ cnts,
                                             int* __restrict__ offs,
                                             ushort* __restrict__ srcs) {
    const int B = blockIdx.x;
    const int hop = B >> 9, bb = B & 511;
    const int dstbase = bb << 6;
    if (dstbase >= N_NODES) return;
    const int bB = cnts[B << 6];
    const int bE = (B == NBKT_TOT - 1) ? E_TOT : cnts[(B + 1) << 6];
    const int cnt = bE - bB;

    __shared__ uint ent[2048];
    __shared__ ushort stg[2048];
    __shared__ int hist[64], cur[64];

    for (int d = threadIdx.x; d < 64; d += 256) hist[d] = 0;
    __syncthreads();
    for (int i = threadIdx.x; i < cnt; i += 256) {
        const uint e = binned[bB + i];
        ent[i] = e;
        atomicAdd(&hist[e >> 16], 1);
    }
    __syncthreads();
    if (threadIdx.x < 64) {
        const int v = hist[threadIdx.x];
        int x = v;
        for (int off = 1; off < 64; off <<= 1) {
            const int t = __shfl_up(x, off, 64);
            if (threadIdx.x >= off) x += t;
        }
        cur[threadIdx.x] = x - v;
        const int gd = dstbase + threadIdx.x;
        if (gd < N_NODES) offs[hop * N_NODES + gd] = bB + x - v;
    }
    __syncthreads();
    for (int i = threadIdx.x; i < cnt; i += 256) {
        const uint e = ent[i];
        const int lp = atomicAdd(&cur[e >> 16], 1);
        stg[lp] = (ushort)(e & 0xffffu);
    }
    __syncthreads();
    for (int i = threadIdx.x; i < cnt; i += 256)
        srcs[bB + i] = stg[i];
}

// ---------------- GIN aggregation, all 3 hops in one launch ----------------
// one wave per (hop,node); lanes split into 2 edge-streams of 32 lanes x uint2
// (one load instruction = 2 rows); combine with shfl_xor(.,32) at the end.
__global__ __launch_bounds__(256) void agg_k(const ushort* __restrict__ xball,
                                             const int* __restrict__ offs,
                                             const ushort* __restrict__ srcs,
                                             const float* __restrict__ eps,
                                             ushort* __restrict__ zb) {
    const int gnode = blockIdx.x * 4 + (threadIdx.x >> 6);   // 0..89999
    const int hop = gnode / N_NODES;
    const int node = gnode - hop * N_NODES;
    const int lane = threadIdx.x & 63;
    const int eh = lane >> 5, cl = lane & 31;
    const float a = 1.0f + eps[hop];
    const uint2* x4 = (const uint2*)(xball + (size_t)(hop + 1) * N_NODES * D);

    float a0 = 0.f, a1 = 0.f, a2 = 0.f, a3 = 0.f;
    if (eh == 0) {
        const uint2 sv = x4[(size_t)node * 32 + cl];
        a0 = a * bf2f((ushort)(sv.x & 0xffff));
        a1 = a * bf2f((ushort)(sv.x >> 16));
        a2 = a * bf2f((ushort)(sv.y & 0xffff));
        a3 = a * bf2f((ushort)(sv.y >> 16));
    }

    const int beg = offs[gnode], end = offs[gnode + 1];
    for (int i = beg; i < end; i += 16) {
        uint2 v[8];
#pragma unroll
        for (int u = 0; u < 8; ++u) {
            const int p = i + 2 * u + eh;
            v[u] = make_uint2(0u, 0u);
            if (p < end) v[u] = x4[(size_t)srcs[p] * 32 + cl];
        }
#pragma unroll
        for (int u = 0; u < 8; ++u) {
            a0 += bf2f((ushort)(v[u].x & 0xffff));
            a1 += bf2f((ushort)(v[u].x >> 16));
            a2 += bf2f((ushort)(v[u].y & 0xffff));
            a3 += bf2f((ushort)(v[u].y >> 16));
        }
    }
    a0 += __shfl_xor(a0, 32);
    a1 += __shfl_xor(a1, 32);
    a2 += __shfl_xor(a2, 32);
    a3 += __shfl_xor(a3, 32);
    if (eh == 0) {
        uint2 o;
        o.x = (uint)f2bf(a0) | ((uint)f2bf(a1) << 16);
        o.y = (uint)f2bf(a2) | ((uint)f2bf(a3) << 16);
        ((uint2*)zb)[(size_t)gnode * 32 + cl] = o;
    }
}

// ---------------- driver ----------------
extern "C" void kernel_launch(void* const* d_in, const int* in_sizes, int n_in,
                              void* d_out, int out_size, void* d_ws, size_t ws_size,
                              hipStream_t stream)
{
    const float* xs  = (const float*)d_in[0];
    const int*   ei  = (const int*)d_in[1];
    const float* lW1 = (const float*)d_in[2];
    const float* lb1 = (const float*)d_in[3];
    const float* lg  = (const float*)d_in[4];
    const float* lbt = (const float*)d_in[5];
    const float* lm  = (const float*)d_in[6];
    const float* lv  = (const float*)d_in[7];
    const float* lW2 = (const float*)d_in[8];
    const float* lb2 = (const float*)d_in[9];
    const float* eps = (const float*)d_in[10];
    const float* cW1 = (const float*)d_in[11];
    const float* cb1 = (const float*)d_in[12];
    const float* cg  = (const float*)d_in[13];
    const float* cbt = (const float*)d_in[14];
    const float* cm  = (const float*)d_in[15];
    const float* cv  = (const float*)d_in[16];
    const float* cW2 = (const float*)d_in[17];
    const float* cb2 = (const float*)d_in[18];
    float* out = (float*)d_out;

    char* ws = (char*)d_ws;
    ushort* xball = (ushort*)ws; ws += (size_t)4 * N_NODES * D * sizeof(ushort);
    ushort* zb    = (ushort*)ws; ws += (size_t)H * N_NODES * D * sizeof(ushort);
    ushort* Wt    = (ushort*)ws; ws += (size_t)8 * D * D * sizeof(ushort);
    float*  scof  = (float*)ws;  ws += (size_t)(4 * 256 + 128) * sizeof(float);
    int* cnts     = (int*)ws;    ws += (size_t)CELLS * sizeof(int);
    int* bsums    = (int*)ws;    ws += 128 * sizeof(int);
    int* offs     = (int*)ws;    ws += (size_t)(M_TOT + 64) * sizeof(int);
    uint* binned  = (uint*)ws;   ws += (size_t)E_TOT * sizeof(uint);
    ushort* srcs  = (ushort*)ws;

    // prep
    prep_w_k<<<8, 256, 0, stream>>>(lW1, lW2, cW1, cW2, Wt);
    scof_k<<<1, 512, 0, stream>>>(lb1, lg, lbt, lm, lv, cb1, cg, cbt, cm, cv,
                                  lb2, cb2, scof);
    conv_k<<<(4 * N_NODES * D / 4 + 255) / 256, 256, 0, stream>>>(
        xs, xball, 4 * N_NODES * D / 4);

    // CSR via multisplit
    bincount_k<<<H * NCH, 256, 0, stream>>>(ei, cnts);
    scanA_k<<<SCAN_NBLK, 1024, 0, stream>>>(cnts, bsums);
    scanB_k<<<1, 128, 0, stream>>>(bsums, SCAN_NBLK);
    scanC_k<<<SCAN_NBLK, 1024, 0, stream>>>(cnts, bsums, offs);
    binplace_k<<<H * NCH, 256, 0, stream>>>(ei, cnts, binned);
    cat_k<<<NBKT_TOT, 256, 0, stream>>>(binned, cnts, offs, srcs);

    // aggregation for all 3 hops, then the fused 4-layer MLP
    agg_k<<<M_TOT / 4, 256, 0, stream>>>(xball, offs, srcs, eps, zb);
    fused4_k<<<(N_NODES + 63) / 64, 256, 0, stream>>>(xball, zb, Wt, scof, out);
}

// Round 6
// 181.967 us; speedup vs baseline: 3.3324x; 1.0577x over previous
//
#include <hip/hip_runtime.h>

#define N_NODES 30000
#define N_EDGES 480000
#define D 128
#define H 3
#define BN_EPS 1e-5f
#define M_TOT (H * N_NODES)
#define E_TOT (H * N_EDGES)

#define NCH 64                       // chunks per hop
#define CHE (N_EDGES / NCH)          // 7500 edges per chunk
#define NBKT 512                     // dst buckets per hop (dst>>6)
#define NBKT_TOT (H * NBKT)          // 1536
#define CELLS (NBKT_TOT * NCH)       // 98304 = 96 * 1024
#define SCAN_NBLK (CELLS / 1024)     // 96
#define CONV_N4 (3 * N_NODES * D / 4)        // slices 1..3 only
#define CONV_BLK ((CONV_N4 + 255) / 256)     // 11250

typedef __attribute__((ext_vector_type(8))) short short8v;   // 8 x bf16
typedef __attribute__((ext_vector_type(4))) float f32x4;     // MFMA accumulator

__device__ __forceinline__ ushort f2bf(float f) {            // RNE f32 -> bf16
    uint u = __float_as_uint(f);
    u += 0x7fffu + ((u >> 16) & 1u);
    return (ushort)(u >> 16);
}
__device__ __forceinline__ float bf2f(ushort b) {
    return __uint_as_float(((uint)b) << 16);
}

// ---------------- merged prep: weights^T + BN coeffs + bf16 conv (slices 1-3)
__global__ __launch_bounds__(256) void prep_k(
    const float* __restrict__ xs,
    const float* __restrict__ lW1, const float* __restrict__ lW2,
    const float* __restrict__ cW1, const float* __restrict__ cW2,
    const float* __restrict__ lb1, const float* __restrict__ lg,
    const float* __restrict__ lbt, const float* __restrict__ lm,
    const float* __restrict__ lv,
    const float* __restrict__ cb1, const float* __restrict__ cg,
    const float* __restrict__ cbt, const float* __restrict__ cm,
    const float* __restrict__ cv,
    const float* __restrict__ lb2, const float* __restrict__ cb2,
    ushort* __restrict__ Wt, float* __restrict__ scof,
    ushort* __restrict__ xball)
{
    const int bid = blockIdx.x;
    const int tid = threadIdx.x;
    if (bid < 8) {                           // transpose+convert weight mat bid
        const float* src;
        if (bid == 0) src = lW1;
        else if (bid == 1) src = lW2;
        else {
            const int k = (bid - 2) >> 1;
            src = ((bid & 1) == 0 ? cW1 : cW2) + (size_t)k * D * D;
        }
        ushort* dst = Wt + (size_t)bid * D * D;
        for (int idx = tid; idx < D * D; idx += 256) {
            const int n = idx >> 7, k = idx & 127;
            dst[idx] = f2bf(src[k * D + n]);
        }
    } else if (bid == 8) {                   // BN scale/offset + total bias
        for (int t = tid; t < 512; t += 256) {
            const int L = t >> 7, c = t & 127;
            float g, v, b, m, bt;
            if (L == 0) { g = lg[c]; v = lv[c]; b = lb1[c]; m = lm[c]; bt = lbt[c]; }
            else {
                const int k = L - 1;
                g = cg[k * D + c]; v = cv[k * D + c]; b = cb1[k * D + c];
                m = cm[k * D + c]; bt = cbt[k * D + c];
            }
            const float s = g * rsqrtf(v + BN_EPS);
            scof[L * 256 + c] = s;
            scof[L * 256 + 128 + c] = (b - m) * s + bt;
        }
        if (tid < 128) {                     // btot = lb2 + sum_k cb2[k]
            float t = lb2[tid];
            for (int k = 0; k < H; ++k) t += cb2[k * D + tid];
            scof[1024 + tid] = t;
        }
    } else {                                 // f32 -> bf16 for xs slices 1..3
        const int i = (bid - 9) * 256 + tid;
        if (i < CONV_N4) {
            const float4 v = ((const float4*)(xs + (size_t)N_NODES * D))[i];
            ushort4 o;
            o.x = f2bf(v.x); o.y = f2bf(v.y); o.z = f2bf(v.z); o.w = f2bf(v.w);
            ((ushort4*)(xball + (size_t)N_NODES * D))[i] = o;
        }
    }
}

// ---------------- Fused 4-layer MLP: out = sum_L relu(bn(X_L@W1+b1))@W2 -----
// One block = 64 rows; accO chains as MFMA C across all 4 layers; single
// f32 write of out. X_0 staged from f32 xs directly; X_{1..3} = zb[hop].
#define LW 136

__global__ __launch_bounds__(256) void fused4_k(
    const float* __restrict__ xs0, const ushort* __restrict__ zb,
    const ushort* __restrict__ Wt, const float* __restrict__ scof,
    float* __restrict__ out)
{
    __shared__ ushort Xs[64 * LW];
    __shared__ ushort Ws[128 * LW];
    const int tid = threadIdx.x;
    const int wave = tid >> 6, lane = tid & 63;
    const int m16 = lane & 15, kq = lane >> 4;
    const int row0 = blockIdx.x * 64;
    const int arow = wave * 16 + m16;

    f32x4 accO[8];
#pragma unroll
    for (int t = 0; t < 8; ++t) accO[t] = (f32x4){0.f, 0.f, 0.f, 0.f};

    for (int L = 0; L < 4; ++L) {
        const ushort* W1t = Wt + (size_t)(2 * L) * D * D;
        const ushort* W2t = W1t + D * D;
        const float* scL = scof + L * 256;

        if (L) __syncthreads();     // prior layer's GEMM2 readers done
        if (L == 0) {
            for (int f = tid; f < 2048; f += 256) {
                const int r = f >> 5, c8 = (f & 31) << 2;
                const int gr = row0 + r;
                ushort4 v = make_ushort4(0, 0, 0, 0);
                if (gr < N_NODES) {
                    const float4 fv = *(const float4*)(xs0 + (size_t)gr * D + c8);
                    v.x = f2bf(fv.x); v.y = f2bf(fv.y);
                    v.z = f2bf(fv.z); v.w = f2bf(fv.w);
                }
                *(ushort4*)(&Xs[r * LW + c8]) = v;
            }
        } else {
            const ushort* X = zb + (size_t)(L - 1) * N_NODES * D;
            for (int f = tid; f < 2048; f += 256) {
                const int r = f >> 5, c8 = (f & 31) << 2;
                ushort4 v = make_ushort4(0, 0, 0, 0);
                const int gr = row0 + r;
                if (gr < N_NODES) v = *(const ushort4*)(X + (size_t)gr * D + c8);
                *(ushort4*)(&Xs[r * LW + c8]) = v;
            }
        }
        for (int f = tid; f < 4096; f += 256) {
            const int n = f >> 5, c8 = (f & 31) << 2;
            *(ushort4*)(&Ws[n * LW + c8]) = *(const ushort4*)(W1t + n * D + c8);
        }
        __syncthreads();

        f32x4 acc[8];
#pragma unroll
        for (int t = 0; t < 8; ++t) acc[t] = (f32x4){0.f, 0.f, 0.f, 0.f};
#pragma unroll
        for (int kk = 0; kk < 4; ++kk) {
            const short8v a = *(const short8v*)(&Xs[arow * LW + kk * 32 + kq * 8]);
#pragma unroll
            for (int t = 0; t < 8; ++t) {
                const short8v b = *(const short8v*)(&Ws[(t * 16 + m16) * LW + kk * 32 + kq * 8]);
                acc[t] = __builtin_amdgcn_mfma_f32_16x16x32_bf16(a, b, acc[t], 0, 0, 0);
            }
        }
        __syncthreads();            // GEMM1 readers done before Xs/Ws overwrite

        // epilogue 1: h = relu(bn(.)) -> bf16 back into Xs; restage Ws = W2
#pragma unroll
        for (int t = 0; t < 8; ++t) {
            const int n = t * 16 + m16;
            const float sc = scL[n], of = scL[128 + n];
#pragma unroll
            for (int r = 0; r < 4; ++r) {
                const int m = wave * 16 + kq * 4 + r;
                Xs[m * LW + n] = f2bf(fmaxf(acc[t][r] * sc + of, 0.f));
            }
        }
        for (int f = tid; f < 4096; f += 256) {
            const int n = f >> 5, c8 = (f & 31) << 2;
            *(ushort4*)(&Ws[n * LW + c8]) = *(const ushort4*)(W2t + n * D + c8);
        }
        __syncthreads();

        // GEMM2 accumulates straight into accO (C-in chaining across layers)
#pragma unroll
        for (int kk = 0; kk < 4; ++kk) {
            const short8v a = *(const short8v*)(&Xs[arow * LW + kk * 32 + kq * 8]);
#pragma unroll
            for (int t = 0; t < 8; ++t) {
                const short8v b = *(const short8v*)(&Ws[(t * 16 + m16) * LW + kk * 32 + kq * 8]);
                accO[t] = __builtin_amdgcn_mfma_f32_16x16x32_bf16(a, b, accO[t], 0, 0, 0);
            }
        }
    }

    const float* btot = scof + 1024;
#pragma unroll
    for (int t = 0; t < 8; ++t) {
        const int n = t * 16 + m16;
        const float bb = btot[n];
#pragma unroll
        for (int r = 0; r < 4; ++r) {
            const int gr = row0 + wave * 16 + kq * 4 + r;
            if (gr < N_NODES) out[(size_t)gr * D + n] = accO[t][r] + bb;
        }
    }
}

// ---------------- CSR build: deterministic two-pass multisplit -------------
__global__ __launch_bounds__(256) void bincount_k(const int* __restrict__ ei,
                                                  int* __restrict__ cnts) {
    __shared__ int hc[NBKT];
    const int chunk = blockIdx.x;
    const int hop = chunk >> 6, c = chunk & 63;
    for (int i = threadIdx.x; i < NBKT; i += 256) hc[i] = 0;
    __syncthreads();
    const int* dstp = ei + (size_t)hop * 2 * N_EDGES + N_EDGES + c * CHE;
    for (int i = threadIdx.x; i < CHE; i += 256)
        atomicAdd(&hc[dstp[i] >> 6], 1);
    __syncthreads();
    for (int b = threadIdx.x; b < NBKT; b += 256)
        cnts[((hop * NBKT + b) << 6) | c] = hc[b];
}

__global__ __launch_bounds__(1024) void scanA_k(int* __restrict__ cnts,
                                                int* __restrict__ bsums) {
    __shared__ int sh[1024];
    const int tid = threadIdx.x;
    const int i = blockIdx.x * 1024 + tid;
    const int v = cnts[i];
    sh[tid] = v;
    __syncthreads();
    int val = v;
    for (int off = 1; off < 1024; off <<= 1) {
        const int t = (tid >= off) ? sh[tid - off] : 0;
        __syncthreads();
        val += t;
        sh[tid] = val;
        __syncthreads();
    }
    cnts[i] = val - v;
    if (tid == 1023) bsums[blockIdx.x] = val;
}

__global__ __launch_bounds__(128) void scanB_k(int* __restrict__ bsums, int nb) {
    __shared__ int sh[128];
    const int tid = threadIdx.x;
    const int v = (tid < nb) ? bsums[tid] : 0;
    sh[tid] = v;
    __syncthreads();
    int val = v;
    for (int off = 1; off < 128; off <<= 1) {
        const int t = (tid >= off) ? sh[tid - off] : 0;
        __syncthreads();
        val += t;
        sh[tid] = val;
        __syncthreads();
    }
    if (tid < nb) bsums[tid] = val - v;
}

__global__ __launch_bounds__(1024) void scanC_k(int* __restrict__ cnts,
                                                const int* __restrict__ bsums,
                                                int* __restrict__ offs) {
    const int i = blockIdx.x * 1024 + threadIdx.x;
    cnts[i] += bsums[blockIdx.x];
    if (i == 0) offs[M_TOT] = E_TOT;
}

__global__ __launch_bounds__(256) void binplace_k(const int* __restrict__ ei,
                                                  const int* __restrict__ cnts,
                                                  uint* __restrict__ binned) {
    __shared__ int cur[NBKT];
    const int chunk = blockIdx.x;
    const int hop = chunk >> 6, c = chunk & 63;
    for (int b = threadIdx.x; b < NBKT; b += 256)
        cur[b] = cnts[((hop * NBKT + b) << 6) | c];
    __syncthreads();
    const int* srcp = ei + (size_t)hop * 2 * N_EDGES + c * CHE;
    const int* dstp = srcp + N_EDGES;
    for (int i = threadIdx.x; i < CHE; i += 256) {
        const int s = srcp[i], d = dstp[i];
        const int slot = atomicAdd(&cur[d >> 6], 1);
        binned[slot] = ((uint)(d & 63) << 16) | (uint)s;
    }
}

__global__ __launch_bounds__(256) void cat_k(const uint* __restrict__ binned,
                                             const int* __restrict__ cnts,
                                             int* __restrict__ offs,
                                             ushort* __restrict__ srcs) {
    const int B = blockIdx.x;
    const int hop = B >> 9, bb = B & 511;
    const int dstbase = bb << 6;
    if (dstbase >= N_NODES) return;
    const int bB = cnts[B << 6];
    const int bE = (B == NBKT_TOT - 1) ? E_TOT : cnts[(B + 1) << 6];
    const int cnt = bE - bB;

    __shared__ uint ent[2048];
    __shared__ ushort stg[2048];
    __shared__ int hist[64], cur[64];

    for (int d = threadIdx.x; d < 64; d += 256) hist[d] = 0;
    __syncthreads();
    for (int i = threadIdx.x; i < cnt; i += 256) {
        const uint e = binned[bB + i];
        ent[i] = e;
        atomicAdd(&hist[e >> 16], 1);
    }
    __syncthreads();
    if (threadIdx.x < 64) {
        const int v = hist[threadIdx.x];
        int x = v;
        for (int off = 1; off < 64; off <<= 1) {
            const int t = __shfl_up(x, off, 64);
            if (threadIdx.x >= off) x += t;
        }
        cur[threadIdx.x] = x - v;
        const int gd = dstbase + threadIdx.x;
        if (gd < N_NODES) offs[hop * N_NODES + gd] = bB + x - v;
    }
    __syncthreads();
    for (int i = threadIdx.x; i < cnt; i += 256) {
        const uint e = ent[i];
        const int lp = atomicAdd(&cur[e >> 16], 1);
        stg[lp] = (ushort)(e & 0xffffu);
    }
    __syncthreads();
    for (int i = threadIdx.x; i < cnt; i += 256)
        srcs[bB + i] = stg[i];
}

// ---------------- GIN aggregation, all 3 hops in one launch ----------------
// one wave per (hop,node); 4 edge-streams of 16 lanes x uint4 (one load
// instruction = one full 256B row; 32 edges in flight per wave). Combine
// streams with shfl_xor(16) + shfl_xor(32).
__global__ __launch_bounds__(256) void agg_k(const ushort* __restrict__ xball,
                                             const int* __restrict__ offs,
                                             const ushort* __restrict__ srcs,
                                             const float* __restrict__ eps,
                                             ushort* __restrict__ zb) {
    const int gnode = blockIdx.x * 4 + (threadIdx.x >> 6);   // 0..89999
    const int hop = gnode / N_NODES;
    const int node = gnode - hop * N_NODES;
    const int lane = threadIdx.x & 63;
    const int eh = lane >> 4;            // edge stream 0..3
    const int cl = lane & 15;            // 16B chunk within the 256B row
    const float a = 1.0f + eps[hop];
    const uint4* x4 = (const uint4*)(xball + (size_t)(hop + 1) * N_NODES * D);

    float acc[8];
#pragma unroll
    for (int q = 0; q < 8; ++q) acc[q] = 0.f;
    if (eh == 0) {                       // self term on stream 0
        const uint4 sv = x4[(size_t)node * 16 + cl];
        const uint w[4] = {sv.x, sv.y, sv.z, sv.w};
#pragma unroll
        for (int q = 0; q < 4; ++q) {
            acc[2 * q]     = a * bf2f((ushort)(w[q] & 0xffff));
            acc[2 * q + 1] = a * bf2f((ushort)(w[q] >> 16));
        }
    }

    const int beg = offs[gnode], end = offs[gnode + 1];
    for (int i = beg; i < end; i += 32) {
        uint4 v[8];
#pragma unroll
        for (int u = 0; u < 8; ++u) {
            const int p = i + u * 4 + eh;
            v[u] = make_uint4(0u, 0u, 0u, 0u);
            if (p < end) v[u] = x4[(size_t)srcs[p] * 16 + cl];
        }
#pragma unroll
        for (int u = 0; u < 8; ++u) {
            const uint w[4] = {v[u].x, v[u].y, v[u].z, v[u].w};
#pragma unroll
            for (int q = 0; q < 4; ++q) {
                acc[2 * q]     += bf2f((ushort)(w[q] & 0xffff));
                acc[2 * q + 1] += bf2f((ushort)(w[q] >> 16));
            }
        }
    }
#pragma unroll
    for (int q = 0; q < 8; ++q) {
        acc[q] += __shfl_xor(acc[q], 16);
        acc[q] += __shfl_xor(acc[q], 32);
    }
    if (eh == 0) {
        uint4 o;
        o.x = (uint)f2bf(acc[0]) | ((uint)f2bf(acc[1]) << 16);
        o.y = (uint)f2bf(acc[2]) | ((uint)f2bf(acc[3]) << 16);
        o.z = (uint)f2bf(acc[4]) | ((uint)f2bf(acc[5]) << 16);
        o.w = (uint)f2bf(acc[6]) | ((uint)f2bf(acc[7]) << 16);
        ((uint4*)zb)[(size_t)gnode * 16 + cl] = o;
    }
}

// ---------------- driver ----------------
extern "C" void kernel_launch(void* const* d_in, const int* in_sizes, int n_in,
                              void* d_out, int out_size, void* d_ws, size_t ws_size,
                              hipStream_t stream)
{
    const float* xs  = (const float*)d_in[0];
    const int*   ei  = (const int*)d_in[1];
    const float* lW1 = (const float*)d_in[2];
    const float* lb1 = (const float*)d_in[3];
    const float* lg  = (const float*)d_in[4];
    const float* lbt = (const float*)d_in[5];
    const float* lm  = (const float*)d_in[6];
    const float* lv  = (const float*)d_in[7];
    const float* lW2 = (const float*)d_in[8];
    const float* lb2 = (const float*)d_in[9];
    const float* eps = (const float*)d_in[10];
    const float* cW1 = (const float*)d_in[11];
    const float* cb1 = (const float*)d_in[12];
    const float* cg  = (const float*)d_in[13];
    const float* cbt = (const float*)d_in[14];
    const float* cm  = (const float*)d_in[15];
    const float* cv  = (const float*)d_in[16];
    const float* cW2 = (const float*)d_in[17];
    const float* cb2 = (const float*)d_in[18];
    float* out = (float*)d_out;

    char* ws = (char*)d_ws;
    ushort* xball = (ushort*)ws; ws += (size_t)4 * N_NODES * D * sizeof(ushort);
    ushort* zb    = (ushort*)ws; ws += (size_t)H * N_NODES * D * sizeof(ushort);
    ushort* Wt    = (ushort*)ws; ws += (size_t)8 * D * D * sizeof(ushort);
    float*  scof  = (float*)ws;  ws += (size_t)(4 * 256 + 128) * sizeof(float);
    int* cnts     = (int*)ws;    ws += (size_t)CELLS * sizeof(int);
    int* bsums    = (int*)ws;    ws += 128 * sizeof(int);
    int* offs     = (int*)ws;    ws += (size_t)(M_TOT + 64) * sizeof(int);
    uint* binned  = (uint*)ws;   ws += (size_t)E_TOT * sizeof(uint);
    ushort* srcs  = (ushort*)ws;

    // merged prep: weights^T (blocks 0-7), BN coeffs (8), bf16 conv (9+)
    prep_k<<<9 + CONV_BLK, 256, 0, stream>>>(xs, lW1, lW2, cW1, cW2,
                                             lb1, lg, lbt, lm, lv,
                                             cb1, cg, cbt, cm, cv,
                                             lb2, cb2, Wt, scof, xball);

    // CSR via multisplit
    bincount_k<<<H * NCH, 256, 0, stream>>>(ei, cnts);
    scanA_k<<<SCAN_NBLK, 1024, 0, stream>>>(cnts, bsums);
    scanB_k<<<1, 128, 0, stream>>>(bsums, SCAN_NBLK);
    scanC_k<<<SCAN_NBLK, 1024, 0, stream>>>(cnts, bsums, offs);
    binplace_k<<<H * NCH, 256, 0, stream>>>(ei, cnts, binned);
    cat_k<<<NBKT_TOT, 256, 0, stream>>>(binned, cnts, offs, srcs);

    // aggregation for all 3 hops, then the fused 4-layer MLP
    agg_k<<<M_TOT / 4, 256, 0, stream>>>(xball, offs, srcs, eps, zb);
    fused4_k<<<(N_NODES + 63) / 64, 256, 0, stream>>>(xs, zb, Wt, scof, out);
}